// Round 6
// baseline (2858.227 us; speedup 1.0000x reference)
//
#include <hip/hip_runtime.h>
#include <cstdint>
#include <cstddef>

#define NN 100000
#define NP 100032
#define NE 800000
#define NG 256
#define NL 5
#define EPS 1e-5f

typedef __bf16 bf16x8 __attribute__((ext_vector_type(8)));
typedef float f32x4 __attribute__((ext_vector_type(4)));

__device__ __forceinline__ float bf2f(unsigned short u) {
  union { unsigned int i; float f; } x; x.i = ((unsigned int)u) << 16; return x.f;
}
__device__ __forceinline__ unsigned short f2bf(float f) {
  union { float f; unsigned int i; } x; x.f = f;
  unsigned int r = x.i + 0x7fffu + ((x.i >> 16) & 1u);
  return (unsigned short)(r >> 16);
}

// ---------------- init: A = bf16(atom_emb[x]) ----------------
__global__ __launch_bounds__(256) void init_h_k(const int* __restrict__ x,
                                                const float* __restrict__ atom_emb,
                                                unsigned short* __restrict__ A) {
  int i = blockIdx.x * 256 + threadIdx.x;   // NN*8 exactly
  int n = i >> 3, c0 = (i & 7) * 8;
  const float* p = atom_emb + (size_t)x[n] * 64 + c0;
  float4 v0 = *(const float4*)p;
  float4 v1 = *(const float4*)(p + 4);
  union { bf16x8 b; unsigned short u[8]; } o;
  o.u[0] = f2bf(v0.x); o.u[1] = f2bf(v0.y); o.u[2] = f2bf(v0.z); o.u[3] = f2bf(v0.w);
  o.u[4] = f2bf(v1.x); o.u[5] = f2bf(v1.y); o.u[6] = f2bf(v1.z); o.u[7] = f2bf(v1.w);
  *(bf16x8*)(A + (size_t)n * 64 + c0) = o.b;
}

// ---------------- weight transpose+convert: Wt[l][col][k] = bf16(W[l][k][col]) ----------------
__global__ __launch_bounds__(256) void wconv_k(const float* __restrict__ W1,
                                               const float* __restrict__ W2,
                                               unsigned short* __restrict__ Wt1,
                                               unsigned short* __restrict__ Wt2) {
  int i = blockIdx.x * 256 + threadIdx.x;
  const int S = NL * 128 * 64;   // 40960
  if (i < S) {
    int l = i / (128 * 64), r = i % (128 * 64);
    int c = r / 64, k = r % 64;
    Wt1[i] = f2bf(W1[(size_t)l * 64 * 128 + (size_t)k * 128 + c]);
  } else if (i < 2 * S) {
    int j = i - S;
    int l = j / (128 * 64), r = j % (128 * 64);
    int c = r / 128, k = r % 128;
    Wt2[j] = f2bf(W2[(size_t)l * 128 * 64 + (size_t)k * 64 + c]);
  }
}

// ---------------- CSR build ----------------
__global__ __launch_bounds__(256) void hist_k(const int* __restrict__ ei,
                                              int* __restrict__ cnt) {
  int e = blockIdx.x * 256 + threadIdx.x;
  if (e >= NE) return;
  atomicAdd(&cnt[ei[NE + e]], 1);
}

__global__ __launch_bounds__(256) void scan1_k(const int* __restrict__ cnt,
                                               int* __restrict__ rs,
                                               int* __restrict__ bsum) {
  __shared__ int sh[256];
  int t = threadIdx.x;
  int base = blockIdx.x * 1024 + t * 4;
  int v0 = 0, v1 = 0, v2 = 0, v3 = 0;
  if (base + 0 < NN) v0 = cnt[base + 0];
  if (base + 1 < NN) v1 = cnt[base + 1];
  if (base + 2 < NN) v2 = cnt[base + 2];
  if (base + 3 < NN) v3 = cnt[base + 3];
  int tsum = v0 + v1 + v2 + v3;
  sh[t] = tsum;
  __syncthreads();
  for (int off = 1; off < 256; off <<= 1) {
    int x = (t >= off) ? sh[t - off] : 0;
    __syncthreads();
    sh[t] += x;
    __syncthreads();
  }
  int excl = sh[t] - tsum;
  if (base + 0 < NN) rs[base + 0] = excl;
  if (base + 1 < NN) rs[base + 1] = excl + v0;
  if (base + 2 < NN) rs[base + 2] = excl + v0 + v1;
  if (base + 3 < NN) rs[base + 3] = excl + v0 + v1 + v2;
  if (t == 255) bsum[blockIdx.x] = sh[255];
}

__global__ void scan2_k(const int* __restrict__ bsum, int* __restrict__ bofs, int nb) {
  if (threadIdx.x == 0 && blockIdx.x == 0) {
    int run = 0;
    for (int i = 0; i < nb; ++i) { bofs[i] = run; run += bsum[i]; }
  }
}

__global__ __launch_bounds__(256) void scan3_k(int* __restrict__ rs,
                                               const int* __restrict__ bofs,
                                               int* __restrict__ cursor) {
  int i = blockIdx.x * 256 + threadIdx.x;
  if (i < NN) {
    int v = rs[i] + bofs[i >> 10];
    rs[i] = v;
    cursor[i] = v;
  }
  if (i == 0) rs[NN] = NE;
}

// XCD-banded scatter (keeps per-band epack slice XCD-local so stores merge)
__global__ __launch_bounds__(256) void scatter_k(const int* __restrict__ ei,
                                                 const int* __restrict__ eattr,
                                                 int* __restrict__ cursor,
                                                 int* __restrict__ epack) {
  int band = blockIdx.x & 7;
  int e = (blockIdx.x >> 3) * 256 + threadIdx.x;
  if (e >= NE) return;
  int d = ei[NE + e];
  if (d / 12500 != band) return;
  int slot = atomicAdd(&cursor[d], 1);
  epack[slot] = (ei[e] << 3) | eattr[e];
}

// ---------------- gather: B[w] = hsrc(w) + sum relu(hsrc(src)+bond[b]) ----------------
// hsrc(n) = MODE ? relu(A[n]*scl+shf) : A[n]   (prev layer's BN2+relu fused)
// R4-proven form: one wave per dst row, 4 edges in flight (es 0-3, cg 0-15).
template <int MODE>
__global__ __launch_bounds__(256) void csr_aggr_k(const int* __restrict__ rowstart,
                                                  const int* __restrict__ epack,
                                                  const float* __restrict__ bond,
                                                  const unsigned short* __restrict__ A,
                                                  const float* __restrict__ scl64,
                                                  const float* __restrict__ shf64,
                                                  unsigned short* __restrict__ B) {
  __shared__ float bl[320];   // bond [5][64] f32
  int tid = threadIdx.x;
  for (int j = tid; j < 320; j += 256) bl[j] = bond[j];
  __syncthreads();
  int w = blockIdx.x * 4 + (tid >> 6);
  int lane = tid & 63;
  int es = lane >> 4, cg = lane & 15, c0 = cg * 4;
  float s0 = 1.f, s1 = 1.f, s2c = 1.f, s3 = 1.f, f0 = 0.f, f1 = 0.f, f2 = 0.f, f3 = 0.f;
  if (MODE) {
    s0 = scl64[c0]; s1 = scl64[c0 + 1]; s2c = scl64[c0 + 2]; s3 = scl64[c0 + 3];
    f0 = shf64[c0]; f1 = shf64[c0 + 1]; f2 = shf64[c0 + 2]; f3 = shf64[c0 + 3];
  }
  int s = rowstart[w], e = rowstart[w + 1];
  float a0 = 0.f, a1 = 0.f, a2 = 0.f, a3 = 0.f;
  for (int base = s; base < e; base += 64) {
    int m = e - base; if (m > 64) m = 64;
    int pk = (lane < m) ? epack[base + lane] : 0;
    int iters = (m + 3) >> 2;
    for (int i = 0; i < iters; ++i) {
      int idx = i * 4 + es;
      int p = __shfl(pk, idx);
      if (idx < m) {
        ushort4 hv = *(const ushort4*)(A + (size_t)(p >> 3) * 64 + c0);
        float4 bv = *(const float4*)&bl[(p & 7) * 64 + c0];
        float v0 = bf2f(hv.x), v1 = bf2f(hv.y), v2 = bf2f(hv.z), v3 = bf2f(hv.w);
        if (MODE) {
          v0 = fmaxf(fmaf(v0, s0, f0), 0.f);
          v1 = fmaxf(fmaf(v1, s1, f1), 0.f);
          v2 = fmaxf(fmaf(v2, s2c, f2), 0.f);
          v3 = fmaxf(fmaf(v3, s3, f3), 0.f);
        }
        a0 += fmaxf(v0 + bv.x, 0.f);
        a1 += fmaxf(v1 + bv.y, 0.f);
        a2 += fmaxf(v2 + bv.z, 0.f);
        a3 += fmaxf(v3 + bv.w, 0.f);
      }
    }
  }
  a0 += __shfl_xor(a0, 16); a0 += __shfl_xor(a0, 32);
  a1 += __shfl_xor(a1, 16); a1 += __shfl_xor(a1, 32);
  a2 += __shfl_xor(a2, 16); a2 += __shfl_xor(a2, 32);
  a3 += __shfl_xor(a3, 16); a3 += __shfl_xor(a3, 32);
  if (es == 0) {
    ushort4 rv = *(const ushort4*)(A + (size_t)w * 64 + c0);
    float r0 = bf2f(rv.x), r1 = bf2f(rv.y), r2 = bf2f(rv.z), r3 = bf2f(rv.w);
    if (MODE) {
      r0 = fmaxf(fmaf(r0, s0, f0), 0.f);
      r1 = fmaxf(fmaf(r1, s1, f1), 0.f);
      r2 = fmaxf(fmaf(r2, s2c, f2), 0.f);
      r3 = fmaxf(fmaf(r3, s3, f3), 0.f);
    }
    ushort4 o;
    o.x = f2bf(a0 + r0); o.y = f2bf(a1 + r1);
    o.z = f2bf(a2 + r2); o.w = f2bf(a3 + r3);
    *(ushort4*)(B + (size_t)w * 64 + c0) = o;
  }
}

// ---------------- bstat: C = B^T B (64x64 f32), S = colsum(B), rows < NN ----------------
__global__ __launch_bounds__(256) void bstat_k(const unsigned short* __restrict__ B,
                                               float* __restrict__ C,
                                               float* __restrict__ S) {
  __shared__ unsigned short Bs[64][72];
  int tid = threadIdx.x;
  int c1 = tid >> 2, c2q = tid & 3;
  float cacc[16];
#pragma unroll
  for (int j = 0; j < 16; ++j) cacc[j] = 0.f;
  float sacc = 0.f;
  int lr = tid >> 2, lseg = tid & 3;
  for (int chunk = blockIdx.x; chunk < NP / 64; chunk += gridDim.x) {
    int grow = chunk * 64 + lr;
    if (grow < NN) {
      *(bf16x8*)&Bs[lr][lseg * 16]     = *(const bf16x8*)(B + (size_t)grow * 64 + lseg * 16);
      *(bf16x8*)&Bs[lr][lseg * 16 + 8] = *(const bf16x8*)(B + (size_t)grow * 64 + lseg * 16 + 8);
    } else {
      *(uint4*)&Bs[lr][lseg * 16]     = make_uint4(0, 0, 0, 0);
      *(uint4*)&Bs[lr][lseg * 16 + 8] = make_uint4(0, 0, 0, 0);
    }
    __syncthreads();
#pragma unroll 2
    for (int n = 0; n < 64; ++n) {
      float a = bf2f(Bs[n][c1]);
      union { bf16x8 b; unsigned short u[8]; } v0, v1;
      v0.b = *(const bf16x8*)&Bs[n][c2q * 16];
      v1.b = *(const bf16x8*)&Bs[n][c2q * 16 + 8];
#pragma unroll
      for (int j = 0; j < 8; ++j) {
        cacc[j]     = fmaf(a, bf2f(v0.u[j]), cacc[j]);
        cacc[8 + j] = fmaf(a, bf2f(v1.u[j]), cacc[8 + j]);
      }
      if (c2q == 0) sacc += a;
    }
    __syncthreads();
  }
#pragma unroll
  for (int j = 0; j < 16; ++j) atomicAdd(&C[c1 * 64 + c2q * 16 + j], cacc[j]);
  if (c2q == 0) atomicAdd(&S[c1], sacc);
}

// ---------------- bnsolve: analytic BN1 -> scl1/shf1 per col (bias cancels) ----------------
// var(z1_c) = (w^T C w)/N - mb^2,  mb = (S·w)/N,  out = scl*(B@w) + (be - scl*mb)
__global__ __launch_bounds__(256) void bnsolve_k(const float* __restrict__ C,
                                                 const float* __restrict__ S,
                                                 const unsigned short* __restrict__ Wt1,
                                                 const float* __restrict__ g,
                                                 const float* __restrict__ be,
                                                 float* __restrict__ scl1,
                                                 float* __restrict__ shf1) {
  int c = blockIdx.x;        // 0..127
  int tid = threadIdx.x;
  __shared__ float wl[64];
  __shared__ float red[256];
  if (tid < 64) wl[tid] = bf2f(Wt1[(size_t)c * 64 + tid]);
  __syncthreads();
  int i = tid >> 2, jq = tid & 3;
  const float* Ci = C + i * 64 + jq * 16;
  float p = 0.f;
#pragma unroll
  for (int j = 0; j < 16; ++j) p = fmaf(Ci[j], wl[jq * 16 + j], p);
  p *= wl[i];
  float mp = (jq == 0) ? S[i] * wl[i] : 0.f;
  red[tid] = p;
  __syncthreads();
  for (int off = 128; off >= 1; off >>= 1) {
    if (tid < off) red[tid] += red[tid + off];
    __syncthreads();
  }
  float qf = red[0];
  __syncthreads();
  red[tid] = mp;
  __syncthreads();
  for (int off = 128; off >= 1; off >>= 1) {
    if (tid < off) red[tid] += red[tid + off];
    __syncthreads();
  }
  if (tid == 0) {
    float mb = red[0] * (1.f / NN);
    float var = fmaxf(qf * (1.f / NN) - mb * mb, 0.f);
    float sc = g[c] * rsqrtf(var + EPS);
    scl1[c] = sc;
    shf1[c] = be[c] - mb * sc;
  }
}

// ---------------- fused gemm1+BN1+relu+gemm2: z1 never leaves LDS ----------------
__global__ __launch_bounds__(256) void gemm12_k(const unsigned short* __restrict__ B,
                                                const unsigned short* __restrict__ Wt1,
                                                const unsigned short* __restrict__ Wt2,
                                                const float* __restrict__ scl1,
                                                const float* __restrict__ shf1,
                                                const float* __restrict__ b2,
                                                unsigned short* __restrict__ z2b,
                                                float* __restrict__ stat2f) {
  __shared__ unsigned short Zs[64][136];   // z1 tile (bf16, post BN1+relu)
  __shared__ float sclS[128], shfS[128], sred[128];
  int tid = threadIdx.x;
  if (tid < 128) { sclS[tid] = scl1[tid]; shfS[tid] = shf1[tid]; sred[tid] = 0.f; }
  __syncthreads();
  int w = tid >> 6, lane = tid & 63;
  int rlo = lane & 15, khi = lane >> 4;
  int row0 = blockIdx.x * 64 + w * 16;
  // phase 1: z1 = B @ W1 (bias cancels in BN), BN1+relu in-register (unrounded z1)
  const bf16x8* ap = (const bf16x8*)(B + (size_t)(row0 + rlo) * 64 + khi * 8);
  bf16x8 a0 = ap[0], a1 = ap[4];
#pragma unroll
  for (int ct = 0; ct < 8; ++ct) {
    const bf16x8* bp = (const bf16x8*)(Wt1 + (size_t)(ct * 16 + rlo) * 64 + khi * 8);
    f32x4 acc;
    acc[0] = 0.f; acc[1] = 0.f; acc[2] = 0.f; acc[3] = 0.f;
    acc = __builtin_amdgcn_mfma_f32_16x16x32_bf16(a0, bp[0], acc, 0, 0, 0);
    acc = __builtin_amdgcn_mfma_f32_16x16x32_bf16(a1, bp[4], acc, 0, 0, 0);
    int c = ct * 16 + rlo;
    float sc = sclS[c], sf = shfS[c];
#pragma unroll
    for (int q = 0; q < 4; ++q)
      Zs[w * 16 + khi * 4 + q][c] = f2bf(fmaxf(fmaf(acc[q], sc, sf), 0.f));
  }
  // phase 2 A-frags: rows w*16.. owned by this wave -> intra-wave LDS dep only
  bf16x8 af0 = *(const bf16x8*)&Zs[w * 16 + rlo][khi * 8];
  bf16x8 af1 = *(const bf16x8*)&Zs[w * 16 + rlo][32 + khi * 8];
  bf16x8 af2 = *(const bf16x8*)&Zs[w * 16 + rlo][64 + khi * 8];
  bf16x8 af3 = *(const bf16x8*)&Zs[w * 16 + rlo][96 + khi * 8];
  __syncthreads();   // all reads done before Zs reused as z2 staging
  f32x4 acc2[4];
#pragma unroll
  for (int ct = 0; ct < 4; ++ct) { acc2[ct][0] = 0.f; acc2[ct][1] = 0.f; acc2[ct][2] = 0.f; acc2[ct][3] = 0.f; }
#pragma unroll
  for (int ct = 0; ct < 4; ++ct) {
    const bf16x8* bp = (const bf16x8*)(Wt2 + (size_t)(ct * 16 + rlo) * 128 + khi * 8);
    acc2[ct] = __builtin_amdgcn_mfma_f32_16x16x32_bf16(af0, bp[0], acc2[ct], 0, 0, 0);
    acc2[ct] = __builtin_amdgcn_mfma_f32_16x16x32_bf16(af1, bp[4], acc2[ct], 0, 0, 0);
    acc2[ct] = __builtin_amdgcn_mfma_f32_16x16x32_bf16(af2, bp[8], acc2[ct], 0, 0, 0);
    acc2[ct] = __builtin_amdgcn_mfma_f32_16x16x32_bf16(af3, bp[12], acc2[ct], 0, 0, 0);
  }
  unsigned short (*Z2)[72] = (unsigned short(*)[72])Zs;
#pragma unroll
  for (int ct = 0; ct < 4; ++ct) {
    int c = ct * 16 + rlo;
    float bs = b2[c];
    float s = 0.f, s2 = 0.f;
#pragma unroll
    for (int q = 0; q < 4; ++q) {
      int brow = w * 16 + khi * 4 + q;
      float v = acc2[ct][q] + bs;
      unsigned short ub = f2bf(v);
      Z2[brow][c] = ub;
      float vf = bf2f(ub);
      if (blockIdx.x * 64 + brow < NN) { s += vf; s2 += vf * vf; }
    }
    atomicAdd(&sred[c], s);
    atomicAdd(&sred[64 + c], s2);
  }
  __syncthreads();
#pragma unroll
  for (int pass = 0; pass < 2; ++pass) {
    int orow = pass * 32 + (tid >> 3), oc0 = (tid & 7) * 8;
    *(bf16x8*)(z2b + (size_t)(blockIdx.x * 64 + orow) * 64 + oc0) =
        *(const bf16x8*)&Z2[orow][oc0];
  }
  if (tid < 128) atomicAdd(&stat2f[(blockIdx.x & 7) * 128 + tid], sred[tid]);
}

// ---------------- BN2 finalize -> scl/shf (64 channels) ----------------
__global__ void finalize2_k(const float* __restrict__ stat2f,
                            const float* __restrict__ g,
                            const float* __restrict__ be,
                            float* __restrict__ scl, float* __restrict__ shf) {
  int c = threadIdx.x;   // 64 threads
  float s = 0.f, s2 = 0.f;
#pragma unroll
  for (int r = 0; r < 8; ++r) { s += stat2f[r * 128 + c]; s2 += stat2f[r * 128 + 64 + c]; }
  float mean = s * (1.f / NN);
  float var = fmaxf(s2 * (1.f / NN) - mean * mean, 0.f);
  float sc = g[c] * rsqrtf(var + EPS);
  scl[c] = sc;
  shf[c] = be[c] - mean * sc;
}

// ---------------- final BN apply (no relu) -> f32 h output; BN2 finalize in prologue ----------------
__global__ __launch_bounds__(256) void bn_final_k(const unsigned short* __restrict__ A,
                                                  const float* __restrict__ stat2f,
                                                  const float* __restrict__ g,
                                                  const float* __restrict__ be,
                                                  float* __restrict__ hf) {
  __shared__ float scl[64], shf[64];
  int tid = threadIdx.x;
  if (tid < 64) {
    float s = 0.f, s2 = 0.f;
#pragma unroll
    for (int r = 0; r < 8; ++r) { s += stat2f[r * 128 + tid]; s2 += stat2f[r * 128 + 64 + tid]; }
    float mean = s * (1.f / NN);
    float var = fmaxf(s2 * (1.f / NN) - mean * mean, 0.f);
    float sc = g[tid] * rsqrtf(var + EPS);
    scl[tid] = sc;
    shf[tid] = be[tid] - mean * sc;
  }
  __syncthreads();
  int i = blockIdx.x * 256 + tid;   // NN*8 exactly
  int n = i >> 3, c0 = (i & 7) * 8;
  union { bf16x8 b; unsigned short u[8]; } raw;
  raw.b = *(const bf16x8*)(A + (size_t)n * 64 + c0);
  float v[8];
#pragma unroll
  for (int j = 0; j < 8; ++j) v[j] = fmaf(bf2f(raw.u[j]), scl[c0 + j], shf[c0 + j]);
  float* p = hf + (size_t)n * 64 + c0;
  *(float4*)(p)     = make_float4(v[0], v[1], v[2], v[3]);
  *(float4*)(p + 4) = make_float4(v[4], v[5], v[6], v[7]);
}

// ---------------- pool: xpool[batch[n]] += h[n]  (batch sorted) ----------------
__global__ __launch_bounds__(256) void pool_k(const float* __restrict__ h,
                                              const int* __restrict__ batch,
                                              float* __restrict__ xpool) {
  int n0 = blockIdx.x * 16;
  int tid = threadIdx.x;
  int r = tid >> 4, c4 = tid & 15;
  int n = n0 + r;
  float4 v = *(const float4*)(h + (size_t)n * 64 + c4 * 4);
  __shared__ int gfirst, gsame;
  __shared__ float red[16][64];
  if (tid == 0) {
    gfirst = batch[n0];
    gsame = (batch[n0] == batch[n0 + 15]) ? 1 : 0;
  }
  *(float4*)&red[r][c4 * 4] = v;
  __syncthreads();
  if (gsame) {
#pragma unroll
    for (int off = 8; off >= 1; off >>= 1) {
      if (r < off) {
        float4 a = *(float4*)&red[r][c4 * 4];
        float4 b = *(float4*)&red[r + off][c4 * 4];
        *(float4*)&red[r][c4 * 4] = make_float4(a.x + b.x, a.y + b.y, a.z + b.z, a.w + b.w);
      }
      __syncthreads();
    }
    if (r == 0) {
      float* p = xpool + (size_t)gfirst * 64 + c4 * 4;
      float4 a = *(float4*)&red[0][c4 * 4];
      atomicAdd(p + 0, a.x); atomicAdd(p + 1, a.y);
      atomicAdd(p + 2, a.z); atomicAdd(p + 3, a.w);
    }
  } else {
    int g = batch[n];
    float* p = xpool + (size_t)g * 64 + c4 * 4;
    atomicAdd(p + 0, v.x); atomicAdd(p + 1, v.y);
    atomicAdd(p + 2, v.z); atomicAdd(p + 3, v.w);
  }
}

extern "C" void kernel_launch(void* const* d_in, const int* in_sizes, int n_in,
                              void* d_out, int out_size, void* d_ws, size_t ws_size,
                              hipStream_t stream) {
  const int* batch = (const int*)d_in[0];
  const int* x = (const int*)d_in[1];
  const int* ei = (const int*)d_in[2];
  const int* eattr = (const int*)d_in[3];
  const float* atom_emb = (const float*)d_in[4];
  const float* bond_emb = (const float*)d_in[5];
  const float* W1 = (const float*)d_in[6];
  const float* g1 = (const float*)d_in[8];
  const float* be1 = (const float*)d_in[9];
  const float* W2 = (const float*)d_in[10];
  const float* b2 = (const float*)d_in[11];
  const float* gbn = (const float*)d_in[12];
  const float* bbn = (const float*)d_in[13];

  float* out = (float*)d_out;
  float* xpool = out;               // 256*64
  float* hf = out + NG * 64;        // final f32 h lives directly in output

  char* ws = (char*)d_ws;
  unsigned short* A   = (unsigned short*)(ws);                      // NP*64 bf16 (h / z2)
  unsigned short* B   = (unsigned short*)(ws + 12804096);           // NP*64 bf16 (z = h+aggr)
  float* statf        = (float*)(ws + 25608192);                    // 5*5184 f32 = 103680 B
  float* scl1b        = (float*)(ws + 25711872);                    // 128+128
  float* shf1b        = scl1b + 128;
  float* scl2b        = (float*)(ws + 25712896);                    // 64+64
  float* shf2b        = scl2b + 64;
  unsigned short* Wt1 = (unsigned short*)(ws + 25713408);           // 5*128*64 bf16
  unsigned short* Wt2 = (unsigned short*)(ws + 25795328);           // 5*64*128 bf16
  int* rowstart       = (int*)(ws + 25877248);                      // NP+1 ints
  int* epack          = (int*)(ws + 26277888);                      // NE ints -> ends ~29.5MB
  // CSR build temporaries alias B region (dead until first csr_aggr)
  int* cnt    = (int*)(ws + 12804096);
  int* cursor = (int*)(ws + 12804096 + 1048576);
  int* bsum   = (int*)(ws + 12804096 + 2097152);
  int* bofs   = bsum + 128;

  init_h_k<<<NN * 8 / 256, 256, 0, stream>>>(x, atom_emb, A);
  wconv_k<<<(2 * NL * 128 * 64 + 255) / 256, 256, 0, stream>>>(W1, W2, Wt1, Wt2);

  // ---- CSR build (edge structure shared by all layers) ----
  hipMemsetAsync(cnt, 0, (size_t)NN * 4, stream);
  hist_k<<<(NE + 255) / 256, 256, 0, stream>>>(ei, cnt);
  scan1_k<<<98, 256, 0, stream>>>(cnt, rowstart, bsum);
  scan2_k<<<1, 64, 0, stream>>>(bsum, bofs, 98);
  scan3_k<<<(NN + 255) / 256, 256, 0, stream>>>(rowstart, bofs, cursor);
  scatter_k<<<8 * ((NE + 255) / 256), 256, 0, stream>>>(ei, eattr, cursor, epack);

  hipMemsetAsync(statf, 0, 103680, stream);
  for (int l = 0; l < NL; ++l) {
    float* Cl    = statf + (size_t)l * 5184;
    float* Sl    = Cl + 4096;
    float* stat2 = Cl + 4160;
    if (l == 0)
      csr_aggr_k<0><<<NN / 4, 256, 0, stream>>>(rowstart, epack, bond_emb, A, scl2b, shf2b, B);
    else
      csr_aggr_k<1><<<NN / 4, 256, 0, stream>>>(rowstart, epack, bond_emb, A, scl2b, shf2b, B);
    bstat_k<<<1024, 256, 0, stream>>>(B, Cl, Sl);
    bnsolve_k<<<128, 256, 0, stream>>>(Cl, Sl, Wt1 + (size_t)l * 128 * 64,
                                       g1 + (size_t)l * 128, be1 + (size_t)l * 128,
                                       scl1b, shf1b);
    gemm12_k<<<NP / 64, 256, 0, stream>>>(B, Wt1 + (size_t)l * 128 * 64,
                                          Wt2 + (size_t)l * 64 * 128,
                                          scl1b, shf1b, b2 + (size_t)l * 64, A, stat2);
    if (l < NL - 1)
      finalize2_k<<<1, 64, 0, stream>>>(stat2, gbn + (size_t)l * 64, bbn + (size_t)l * 64,
                                        scl2b, shf2b);
  }

  bn_final_k<<<NN * 8 / 256, 256, 0, stream>>>(A, statf + (size_t)(NL - 1) * 5184 + 4160,
                                               gbn + (size_t)(NL - 1) * 64,
                                               bbn + (size_t)(NL - 1) * 64, hf);

  hipMemsetAsync(xpool, 0, (size_t)NG * 64 * 4, stream);
  pool_k<<<NN / 16, 256, 0, stream>>>(hf, batch, xpool);
}

// Round 7
// 714.084 us; speedup vs baseline: 4.0026x; 4.0026x over previous
//
#include <hip/hip_runtime.h>
#include <cstdint>
#include <cstddef>

#define NN 100000
#define NP 100032
#define NE 800000
#define NG 256
#define NL 5
#define EPS 1e-5f

typedef __bf16 bf16x8 __attribute__((ext_vector_type(8)));
typedef float f32x4 __attribute__((ext_vector_type(4)));

__device__ __forceinline__ float bf2f(unsigned short u) {
  union { unsigned int i; float f; } x; x.i = ((unsigned int)u) << 16; return x.f;
}
__device__ __forceinline__ unsigned short f2bf(float f) {
  union { float f; unsigned int i; } x; x.f = f;
  unsigned int r = x.i + 0x7fffu + ((x.i >> 16) & 1u);
  return (unsigned short)(r >> 16);
}

// ---------------- init: A = bf16(atom_emb[x]) ----------------
__global__ __launch_bounds__(256) void init_h_k(const int* __restrict__ x,
                                                const float* __restrict__ atom_emb,
                                                unsigned short* __restrict__ A) {
  int i = blockIdx.x * 256 + threadIdx.x;   // NN*8 exactly
  int n = i >> 3, c0 = (i & 7) * 8;
  const float* p = atom_emb + (size_t)x[n] * 64 + c0;
  float4 v0 = *(const float4*)p;
  float4 v1 = *(const float4*)(p + 4);
  union { bf16x8 b; unsigned short u[8]; } o;
  o.u[0] = f2bf(v0.x); o.u[1] = f2bf(v0.y); o.u[2] = f2bf(v0.z); o.u[3] = f2bf(v0.w);
  o.u[4] = f2bf(v1.x); o.u[5] = f2bf(v1.y); o.u[6] = f2bf(v1.z); o.u[7] = f2bf(v1.w);
  *(bf16x8*)(A + (size_t)n * 64 + c0) = o.b;
}

// ---------------- weight transpose+convert: Wt[l][col][k] = bf16(W[l][k][col]) ----------------
__global__ __launch_bounds__(256) void wconv_k(const float* __restrict__ W1,
                                               const float* __restrict__ W2,
                                               unsigned short* __restrict__ Wt1,
                                               unsigned short* __restrict__ Wt2) {
  int i = blockIdx.x * 256 + threadIdx.x;
  const int S = NL * 128 * 64;   // 40960
  if (i < S) {
    int l = i / (128 * 64), r = i % (128 * 64);
    int c = r / 64, k = r % 64;
    Wt1[i] = f2bf(W1[(size_t)l * 64 * 128 + (size_t)k * 128 + c]);
  } else if (i < 2 * S) {
    int j = i - S;
    int l = j / (128 * 64), r = j % (128 * 64);
    int c = r / 128, k = r % 128;
    Wt2[j] = f2bf(W2[(size_t)l * 128 * 64 + (size_t)k * 64 + c]);
  }
}

// ---------------- CSR build ----------------
__global__ __launch_bounds__(256) void hist_k(const int* __restrict__ ei,
                                              int* __restrict__ cnt) {
  int e = blockIdx.x * 256 + threadIdx.x;
  if (e >= NE) return;
  atomicAdd(&cnt[ei[NE + e]], 1);
}

__global__ __launch_bounds__(256) void scan1_k(const int* __restrict__ cnt,
                                               int* __restrict__ rs,
                                               int* __restrict__ bsum) {
  __shared__ int sh[256];
  int t = threadIdx.x;
  int base = blockIdx.x * 1024 + t * 4;
  int v0 = 0, v1 = 0, v2 = 0, v3 = 0;
  if (base + 0 < NN) v0 = cnt[base + 0];
  if (base + 1 < NN) v1 = cnt[base + 1];
  if (base + 2 < NN) v2 = cnt[base + 2];
  if (base + 3 < NN) v3 = cnt[base + 3];
  int tsum = v0 + v1 + v2 + v3;
  sh[t] = tsum;
  __syncthreads();
  for (int off = 1; off < 256; off <<= 1) {
    int x = (t >= off) ? sh[t - off] : 0;
    __syncthreads();
    sh[t] += x;
    __syncthreads();
  }
  int excl = sh[t] - tsum;
  if (base + 0 < NN) rs[base + 0] = excl;
  if (base + 1 < NN) rs[base + 1] = excl + v0;
  if (base + 2 < NN) rs[base + 2] = excl + v0 + v1;
  if (base + 3 < NN) rs[base + 3] = excl + v0 + v1 + v2;
  if (t == 255) bsum[blockIdx.x] = sh[255];
}

__global__ void scan2_k(const int* __restrict__ bsum, int* __restrict__ bofs, int nb) {
  if (threadIdx.x == 0 && blockIdx.x == 0) {
    int run = 0;
    for (int i = 0; i < nb; ++i) { bofs[i] = run; run += bsum[i]; }
  }
}

__global__ __launch_bounds__(256) void scan3_k(int* __restrict__ rs,
                                               const int* __restrict__ bofs,
                                               int* __restrict__ cursor) {
  int i = blockIdx.x * 256 + threadIdx.x;
  if (i < NN) {
    int v = rs[i] + bofs[i >> 10];
    rs[i] = v;
    cursor[i] = v;
  }
  if (i == 0) rs[NN] = NE;
}

// XCD-banded scatter (keeps per-band epack slice XCD-local so stores merge)
__global__ __launch_bounds__(256) void scatter_k(const int* __restrict__ ei,
                                                 const int* __restrict__ eattr,
                                                 int* __restrict__ cursor,
                                                 int* __restrict__ epack) {
  int band = blockIdx.x & 7;
  int e = (blockIdx.x >> 3) * 256 + threadIdx.x;
  if (e >= NE) return;
  int d = ei[NE + e];
  if (d / 12500 != band) return;
  int slot = atomicAdd(&cursor[d], 1);
  epack[slot] = (ei[e] << 3) | eattr[e];
}

// ---------------- gather: B[w] = hsrc(w) + sum relu(hsrc(src)+bond[b]) ----------------
// hsrc(n) = MODE ? relu(A[n]*scl+shf) : A[n]   (prev layer's BN2+relu fused)
// 8-wide: lane = (es 0-7, cg 0-7); 8 edges in flight, each lane loads bf16x8 (16B).
template <int MODE>
__global__ __launch_bounds__(256) void csr_aggr_k(const int* __restrict__ rowstart,
                                                  const int* __restrict__ epack,
                                                  const float* __restrict__ bond,
                                                  const unsigned short* __restrict__ A,
                                                  const float* __restrict__ scl64,
                                                  const float* __restrict__ shf64,
                                                  unsigned short* __restrict__ B) {
  __shared__ float bl[320];   // bond [5][64] f32
  int tid = threadIdx.x;
  for (int j = tid; j < 320; j += 256) bl[j] = bond[j];
  __syncthreads();
  int w = blockIdx.x * 4 + (tid >> 6);
  int lane = tid & 63;
  int es = lane >> 3, cg = lane & 7, c0 = cg * 8;
  float sc[8], sf[8];
  if (MODE) {
    float4 s0 = *(const float4*)(scl64 + c0), s1 = *(const float4*)(scl64 + c0 + 4);
    float4 f0 = *(const float4*)(shf64 + c0), f1 = *(const float4*)(shf64 + c0 + 4);
    sc[0]=s0.x; sc[1]=s0.y; sc[2]=s0.z; sc[3]=s0.w; sc[4]=s1.x; sc[5]=s1.y; sc[6]=s1.z; sc[7]=s1.w;
    sf[0]=f0.x; sf[1]=f0.y; sf[2]=f0.z; sf[3]=f0.w; sf[4]=f1.x; sf[5]=f1.y; sf[6]=f1.z; sf[7]=f1.w;
  }
  int s = rowstart[w], e = rowstart[w + 1];
  float acc[8];
#pragma unroll
  for (int j = 0; j < 8; ++j) acc[j] = 0.f;
  for (int base = s; base < e; base += 64) {
    int m = e - base; if (m > 64) m = 64;
    int pk = (lane < m) ? epack[base + lane] : 0;
    int iters = (m + 7) >> 3;
    for (int i = 0; i < iters; ++i) {
      int idx = i * 8 + es;
      int p = __shfl(pk, idx);
      if (idx < m) {
        union { bf16x8 b; unsigned short u[8]; } hv;
        hv.b = *(const bf16x8*)(A + (size_t)(p >> 3) * 64 + c0);
        const float* bp = &bl[(p & 7) * 64 + c0];
        float4 b0 = *(const float4*)(bp);
        float4 b1 = *(const float4*)(bp + 4);
        float bb[8] = {b0.x, b0.y, b0.z, b0.w, b1.x, b1.y, b1.z, b1.w};
#pragma unroll
        for (int j = 0; j < 8; ++j) {
          float v = bf2f(hv.u[j]);
          if (MODE) v = fmaxf(fmaf(v, sc[j], sf[j]), 0.f);
          acc[j] += fmaxf(v + bb[j], 0.f);
        }
      }
    }
  }
#pragma unroll
  for (int j = 0; j < 8; ++j) {
    acc[j] += __shfl_xor(acc[j], 8);
    acc[j] += __shfl_xor(acc[j], 16);
    acc[j] += __shfl_xor(acc[j], 32);
  }
  if (es == 0) {
    union { bf16x8 b; unsigned short u[8]; } rv, o;
    rv.b = *(const bf16x8*)(A + (size_t)w * 64 + c0);
#pragma unroll
    for (int j = 0; j < 8; ++j) {
      float r = bf2f(rv.u[j]);
      if (MODE) r = fmaxf(fmaf(r, sc[j], sf[j]), 0.f);
      o.u[j] = f2bf(acc[j] + r);
    }
    *(bf16x8*)(B + (size_t)w * 64 + c0) = o.b;
  }
}

// ---------------- bstat (MFMA): per-block partial of C = B^T B and S = colsum(B) ----------------
// Grid MUST be 256. Block writes its own 4160-f32 slice (4096 C + 64 S). No atomics.
__global__ __launch_bounds__(256) void bstat_k(const unsigned short* __restrict__ B,
                                               float* __restrict__ Ppart) {
  __shared__ unsigned short Bs[32][76];   // pad 76: khi-groups land on distinct bank sets
  __shared__ float sred[64];
  int tid = threadIdx.x;
  int w = tid >> 6, lane = tid & 63;
  int rlo = lane & 15, khi = lane >> 4;
  int lr = tid >> 3, c8 = (tid & 7) * 8;
  f32x4 acc[4];
#pragma unroll
  for (int ct = 0; ct < 4; ++ct) { acc[ct][0] = 0.f; acc[ct][1] = 0.f; acc[ct][2] = 0.f; acc[ct][3] = 0.f; }
  float sacc[8];
#pragma unroll
  for (int j = 0; j < 8; ++j) sacc[j] = 0.f;
  for (int chunk = blockIdx.x; chunk < NP / 32; chunk += 256) {
    int grow = chunk * 32 + lr;
    union { bf16x8 b; unsigned short u[8]; ushort4 h[2]; } v;
    if (grow < NN) v.b = *(const bf16x8*)(B + (size_t)grow * 64 + c8);
    else { v.h[0] = make_ushort4(0,0,0,0); v.h[1] = make_ushort4(0,0,0,0); }
    __syncthreads();               // previous chunk's fragment reads complete
    *(ushort4*)&Bs[lr][c8] = v.h[0];
    *(ushort4*)&Bs[lr][c8 + 4] = v.h[1];
#pragma unroll
    for (int j = 0; j < 8; ++j) sacc[j] += bf2f(v.u[j]);
    __syncthreads();
    union { bf16x8 b; unsigned short u[8]; } afr, bfr;
#pragma unroll
    for (int j = 0; j < 8; ++j) afr.u[j] = Bs[khi * 8 + j][w * 16 + rlo];
#pragma unroll
    for (int ct = 0; ct < 4; ++ct) {
#pragma unroll
      for (int j = 0; j < 8; ++j) bfr.u[j] = Bs[khi * 8 + j][ct * 16 + rlo];
      acc[ct] = __builtin_amdgcn_mfma_f32_16x16x32_bf16(afr.b, bfr.b, acc[ct], 0, 0, 0);
    }
  }
  float* cp = Ppart + (size_t)blockIdx.x * 4160;
#pragma unroll
  for (int ct = 0; ct < 4; ++ct)
#pragma unroll
    for (int q = 0; q < 4; ++q)
      cp[(w * 16 + khi * 4 + q) * 64 + ct * 16 + rlo] = acc[ct][q];
  if (tid < 64) sred[tid] = 0.f;
  __syncthreads();
#pragma unroll
  for (int j = 0; j < 8; ++j) atomicAdd(&sred[c8 + j], sacc[j]);
  __syncthreads();
  if (tid < 64) cp[4096 + tid] = sred[tid];
}

// ---------------- reduce 256 partials -> Cfull[4096] + Sfull[64] ----------------
__global__ __launch_bounds__(256) void reduce_k(const float* __restrict__ Ppart,
                                                float* __restrict__ Cfull) {
  int idx = blockIdx.x * 256 + threadIdx.x;
  if (idx >= 4160) return;
  float s = 0.f;
#pragma unroll 8
  for (int g = 0; g < 256; ++g) s += Ppart[(size_t)g * 4160 + idx];
  Cfull[idx] = s;
}

// ---------------- bnsolve: analytic BN1 -> scl1/shf1 per col (bias cancels) ----------------
__global__ __launch_bounds__(256) void bnsolve_k(const float* __restrict__ C,
                                                 const float* __restrict__ S,
                                                 const unsigned short* __restrict__ Wt1,
                                                 const float* __restrict__ g,
                                                 const float* __restrict__ be,
                                                 float* __restrict__ scl1,
                                                 float* __restrict__ shf1) {
  int c = blockIdx.x;        // 0..127
  int tid = threadIdx.x;
  __shared__ float wl[64];
  __shared__ float red[256];
  if (tid < 64) wl[tid] = bf2f(Wt1[(size_t)c * 64 + tid]);
  __syncthreads();
  int i = tid >> 2, jq = tid & 3;
  const float* Ci = C + i * 64 + jq * 16;
  float p = 0.f;
#pragma unroll
  for (int j = 0; j < 16; ++j) p = fmaf(Ci[j], wl[jq * 16 + j], p);
  p *= wl[i];
  float mp = (jq == 0) ? S[i] * wl[i] : 0.f;
  red[tid] = p;
  __syncthreads();
  for (int off = 128; off >= 1; off >>= 1) {
    if (tid < off) red[tid] += red[tid + off];
    __syncthreads();
  }
  float qf = red[0];
  __syncthreads();
  red[tid] = mp;
  __syncthreads();
  for (int off = 128; off >= 1; off >>= 1) {
    if (tid < off) red[tid] += red[tid + off];
    __syncthreads();
  }
  if (tid == 0) {
    float mb = red[0] * (1.f / NN);
    float var = fmaxf(qf * (1.f / NN) - mb * mb, 0.f);
    float sc = g[c] * rsqrtf(var + EPS);
    scl1[c] = sc;
    shf1[c] = be[c] - mb * sc;
  }
}

// ---------------- fused gemm1+BN1+relu+gemm2: z1 never leaves LDS ----------------
__global__ __launch_bounds__(256) void gemm12_k(const unsigned short* __restrict__ B,
                                                const unsigned short* __restrict__ Wt1,
                                                const unsigned short* __restrict__ Wt2,
                                                const float* __restrict__ scl1,
                                                const float* __restrict__ shf1,
                                                const float* __restrict__ b2,
                                                unsigned short* __restrict__ z2b,
                                                float* __restrict__ stat2f) {
  __shared__ unsigned short Zs[64][136];   // z1 tile (bf16, post BN1+relu)
  __shared__ float sclS[128], shfS[128], sred[128];
  int tid = threadIdx.x;
  if (tid < 128) { sclS[tid] = scl1[tid]; shfS[tid] = shf1[tid]; sred[tid] = 0.f; }
  __syncthreads();
  int w = tid >> 6, lane = tid & 63;
  int rlo = lane & 15, khi = lane >> 4;
  int row0 = blockIdx.x * 64 + w * 16;
  // phase 1: z1 = B @ W1 (bias cancels in BN), BN1+relu in-register (unrounded z1)
  const bf16x8* ap = (const bf16x8*)(B + (size_t)(row0 + rlo) * 64 + khi * 8);
  bf16x8 a0 = ap[0], a1 = ap[4];
#pragma unroll
  for (int ct = 0; ct < 8; ++ct) {
    const bf16x8* bp = (const bf16x8*)(Wt1 + (size_t)(ct * 16 + rlo) * 64 + khi * 8);
    f32x4 acc;
    acc[0] = 0.f; acc[1] = 0.f; acc[2] = 0.f; acc[3] = 0.f;
    acc = __builtin_amdgcn_mfma_f32_16x16x32_bf16(a0, bp[0], acc, 0, 0, 0);
    acc = __builtin_amdgcn_mfma_f32_16x16x32_bf16(a1, bp[4], acc, 0, 0, 0);
    int c = ct * 16 + rlo;
    float sc = sclS[c], sf = shfS[c];
#pragma unroll
    for (int q = 0; q < 4; ++q)
      Zs[w * 16 + khi * 4 + q][c] = f2bf(fmaxf(fmaf(acc[q], sc, sf), 0.f));
  }
  // phase 2 A-frags: rows w*16.. owned by this wave -> intra-wave LDS dep only
  bf16x8 af0 = *(const bf16x8*)&Zs[w * 16 + rlo][khi * 8];
  bf16x8 af1 = *(const bf16x8*)&Zs[w * 16 + rlo][32 + khi * 8];
  bf16x8 af2 = *(const bf16x8*)&Zs[w * 16 + rlo][64 + khi * 8];
  bf16x8 af3 = *(const bf16x8*)&Zs[w * 16 + rlo][96 + khi * 8];
  __syncthreads();   // all reads done before Zs reused as z2 staging
  f32x4 acc2[4];
#pragma unroll
  for (int ct = 0; ct < 4; ++ct) { acc2[ct][0] = 0.f; acc2[ct][1] = 0.f; acc2[ct][2] = 0.f; acc2[ct][3] = 0.f; }
#pragma unroll
  for (int ct = 0; ct < 4; ++ct) {
    const bf16x8* bp = (const bf16x8*)(Wt2 + (size_t)(ct * 16 + rlo) * 128 + khi * 8);
    acc2[ct] = __builtin_amdgcn_mfma_f32_16x16x32_bf16(af0, bp[0], acc2[ct], 0, 0, 0);
    acc2[ct] = __builtin_amdgcn_mfma_f32_16x16x32_bf16(af1, bp[4], acc2[ct], 0, 0, 0);
    acc2[ct] = __builtin_amdgcn_mfma_f32_16x16x32_bf16(af2, bp[8], acc2[ct], 0, 0, 0);
    acc2[ct] = __builtin_amdgcn_mfma_f32_16x16x32_bf16(af3, bp[12], acc2[ct], 0, 0, 0);
  }
  unsigned short (*Z2)[72] = (unsigned short(*)[72])Zs;
#pragma unroll
  for (int ct = 0; ct < 4; ++ct) {
    int c = ct * 16 + rlo;
    float bs = b2[c];
    float s = 0.f, s2 = 0.f;
#pragma unroll
    for (int q = 0; q < 4; ++q) {
      int brow = w * 16 + khi * 4 + q;
      float v = acc2[ct][q] + bs;
      unsigned short ub = f2bf(v);
      Z2[brow][c] = ub;
      float vf = bf2f(ub);
      if (blockIdx.x * 64 + brow < NN) { s += vf; s2 += vf * vf; }
    }
    atomicAdd(&sred[c], s);
    atomicAdd(&sred[64 + c], s2);
  }
  __syncthreads();
#pragma unroll
  for (int pass = 0; pass < 2; ++pass) {
    int orow = pass * 32 + (tid >> 3), oc0 = (tid & 7) * 8;
    *(bf16x8*)(z2b + (size_t)(blockIdx.x * 64 + orow) * 64 + oc0) =
        *(const bf16x8*)&Z2[orow][oc0];
  }
  if (tid < 128) atomicAdd(&stat2f[(blockIdx.x & 7) * 128 + tid], sred[tid]);
}

// ---------------- BN2 finalize -> scl/shf (64 channels) ----------------
__global__ void finalize2_k(const float* __restrict__ stat2f,
                            const float* __restrict__ g,
                            const float* __restrict__ be,
                            float* __restrict__ scl, float* __restrict__ shf) {
  int c = threadIdx.x;   // 64 threads
  float s = 0.f, s2 = 0.f;
#pragma unroll
  for (int r = 0; r < 8; ++r) { s += stat2f[r * 128 + c]; s2 += stat2f[r * 128 + 64 + c]; }
  float mean = s * (1.f / NN);
  float var = fmaxf(s2 * (1.f / NN) - mean * mean, 0.f);
  float sc = g[c] * rsqrtf(var + EPS);
  scl[c] = sc;
  shf[c] = be[c] - mean * sc;
}

// ---------------- final BN apply (no relu) -> f32 h output; BN2 finalize in prologue ----------------
__global__ __launch_bounds__(256) void bn_final_k(const unsigned short* __restrict__ A,
                                                  const float* __restrict__ stat2f,
                                                  const float* __restrict__ g,
                                                  const float* __restrict__ be,
                                                  float* __restrict__ hf) {
  __shared__ float scl[64], shf[64];
  int tid = threadIdx.x;
  if (tid < 64) {
    float s = 0.f, s2 = 0.f;
#pragma unroll
    for (int r = 0; r < 8; ++r) { s += stat2f[r * 128 + tid]; s2 += stat2f[r * 128 + 64 + tid]; }
    float mean = s * (1.f / NN);
    float var = fmaxf(s2 * (1.f / NN) - mean * mean, 0.f);
    float sc = g[tid] * rsqrtf(var + EPS);
    scl[tid] = sc;
    shf[tid] = be[tid] - mean * sc;
  }
  __syncthreads();
  int i = blockIdx.x * 256 + tid;   // NN*8 exactly
  int n = i >> 3, c0 = (i & 7) * 8;
  union { bf16x8 b; unsigned short u[8]; } raw;
  raw.b = *(const bf16x8*)(A + (size_t)n * 64 + c0);
  float v[8];
#pragma unroll
  for (int j = 0; j < 8; ++j) v[j] = fmaf(bf2f(raw.u[j]), scl[c0 + j], shf[c0 + j]);
  float* p = hf + (size_t)n * 64 + c0;
  *(float4*)(p)     = make_float4(v[0], v[1], v[2], v[3]);
  *(float4*)(p + 4) = make_float4(v[4], v[5], v[6], v[7]);
}

// ---------------- pool: xpool[batch[n]] += h[n]  (batch sorted) ----------------
__global__ __launch_bounds__(256) void pool_k(const float* __restrict__ h,
                                              const int* __restrict__ batch,
                                              float* __restrict__ xpool) {
  int n0 = blockIdx.x * 16;
  int tid = threadIdx.x;
  int r = tid >> 4, c4 = tid & 15;
  int n = n0 + r;
  float4 v = *(const float4*)(h + (size_t)n * 64 + c4 * 4);
  __shared__ int gfirst, gsame;
  __shared__ float red[16][64];
  if (tid == 0) {
    gfirst = batch[n0];
    gsame = (batch[n0] == batch[n0 + 15]) ? 1 : 0;
  }
  *(float4*)&red[r][c4 * 4] = v;
  __syncthreads();
  if (gsame) {
#pragma unroll
    for (int off = 8; off >= 1; off >>= 1) {
      if (r < off) {
        float4 a = *(float4*)&red[r][c4 * 4];
        float4 b = *(float4*)&red[r + off][c4 * 4];
        *(float4*)&red[r][c4 * 4] = make_float4(a.x + b.x, a.y + b.y, a.z + b.z, a.w + b.w);
      }
      __syncthreads();
    }
    if (r == 0) {
      float* p = xpool + (size_t)gfirst * 64 + c4 * 4;
      float4 a = *(float4*)&red[0][c4 * 4];
      atomicAdd(p + 0, a.x); atomicAdd(p + 1, a.y);
      atomicAdd(p + 2, a.z); atomicAdd(p + 3, a.w);
    }
  } else {
    int g = batch[n];
    float* p = xpool + (size_t)g * 64 + c4 * 4;
    atomicAdd(p + 0, v.x); atomicAdd(p + 1, v.y);
    atomicAdd(p + 2, v.z); atomicAdd(p + 3, v.w);
  }
}

extern "C" void kernel_launch(void* const* d_in, const int* in_sizes, int n_in,
                              void* d_out, int out_size, void* d_ws, size_t ws_size,
                              hipStream_t stream) {
  const int* batch = (const int*)d_in[0];
  const int* x = (const int*)d_in[1];
  const int* ei = (const int*)d_in[2];
  const int* eattr = (const int*)d_in[3];
  const float* atom_emb = (const float*)d_in[4];
  const float* bond_emb = (const float*)d_in[5];
  const float* W1 = (const float*)d_in[6];
  const float* g1 = (const float*)d_in[8];
  const float* be1 = (const float*)d_in[9];
  const float* W2 = (const float*)d_in[10];
  const float* b2 = (const float*)d_in[11];
  const float* gbn = (const float*)d_in[12];
  const float* bbn = (const float*)d_in[13];

  float* out = (float*)d_out;
  float* xpool = out;               // 256*64
  float* hf = out + NG * 64;        // final f32 h lives directly in output

  char* ws = (char*)d_ws;
  unsigned short* A   = (unsigned short*)(ws);                      // NP*64 bf16 (h / z2)
  unsigned short* B   = (unsigned short*)(ws + 12804096);           // NP*64 bf16 (z = h+aggr)
  float* stat2f       = (float*)(ws + 25608192);                    // 5*1024 f32 = 20480 B
  float* scl1b        = (float*)(ws + 25628672);                    // 128+128
  float* shf1b        = scl1b + 128;
  float* scl2b        = (float*)(ws + 25629696);                    // 64+64
  float* shf2b        = scl2b + 64;
  float* Cfull        = (float*)(ws + 25630208);                    // 4160 f32
  unsigned short* Wt1 = (unsigned short*)(ws + 25646848);           // 5*128*64 bf16
  unsigned short* Wt2 = (unsigned short*)(ws + 25728768);           // 5*64*128 bf16
  int* rowstart       = (int*)(ws + 25810688);                      // NN+1 ints
  int* epack          = (int*)(ws + 26210704);                      // NE ints
  float* Ppart        = (float*)(ws + 29410704);                    // 256*4160 f32 = 4.26 MB
  // CSR build temporaries alias B region (dead until first csr_aggr)
  int* cnt    = (int*)(ws + 12804096);
  int* cursor = (int*)(ws + 12804096 + 1048576);
  int* bsum   = (int*)(ws + 12804096 + 2097152);
  int* bofs   = bsum + 128;

  init_h_k<<<NN * 8 / 256, 256, 0, stream>>>(x, atom_emb, A);
  wconv_k<<<(2 * NL * 128 * 64 + 255) / 256, 256, 0, stream>>>(W1, W2, Wt1, Wt2);

  // ---- CSR build (edge structure shared by all layers) ----
  hipMemsetAsync(cnt, 0, (size_t)NN * 4, stream);
  hist_k<<<(NE + 255) / 256, 256, 0, stream>>>(ei, cnt);
  scan1_k<<<98, 256, 0, stream>>>(cnt, rowstart, bsum);
  scan2_k<<<1, 64, 0, stream>>>(bsum, bofs, 98);
  scan3_k<<<(NN + 255) / 256, 256, 0, stream>>>(rowstart, bofs, cursor);
  scatter_k<<<8 * ((NE + 255) / 256), 256, 0, stream>>>(ei, eattr, cursor, epack);

  hipMemsetAsync(stat2f, 0, 20480, stream);
  for (int l = 0; l < NL; ++l) {
    float* stat2 = stat2f + (size_t)l * 1024;
    if (l == 0)
      csr_aggr_k<0><<<NN / 4, 256, 0, stream>>>(rowstart, epack, bond_emb, A, scl2b, shf2b, B);
    else
      csr_aggr_k<1><<<NN / 4, 256, 0, stream>>>(rowstart, epack, bond_emb, A, scl2b, shf2b, B);
    bstat_k<<<256, 256, 0, stream>>>(B, Ppart);
    reduce_k<<<17, 256, 0, stream>>>(Ppart, Cfull);
    bnsolve_k<<<128, 256, 0, stream>>>(Cfull, Cfull + 4096, Wt1 + (size_t)l * 128 * 64,
                                       g1 + (size_t)l * 128, be1 + (size_t)l * 128,
                                       scl1b, shf1b);
    gemm12_k<<<NP / 64, 256, 0, stream>>>(B, Wt1 + (size_t)l * 128 * 64,
                                          Wt2 + (size_t)l * 64 * 128,
                                          scl1b, shf1b, b2 + (size_t)l * 64, A, stat2);
    if (l < NL - 1)
      finalize2_k<<<1, 64, 0, stream>>>(stat2, gbn + (size_t)l * 64, bbn + (size_t)l * 64,
                                        scl2b, shf2b);
  }

  bn_final_k<<<NN * 8 / 256, 256, 0, stream>>>(A, stat2f + (size_t)(NL - 1) * 1024,
                                               gbn + (size_t)(NL - 1) * 64,
                                               bbn + (size_t)(NL - 1) * 64, hf);

  hipMemsetAsync(xpool, 0, (size_t)NG * 64 * 4, stream);
  pool_k<<<NN / 16, 256, 0, stream>>>(hf, batch, xpool);
}

// Round 8
// 600.414 us; speedup vs baseline: 4.7604x; 1.1893x over previous
//
#include <hip/hip_runtime.h>
#include <cstdint>
#include <cstddef>

#define NN 100000
#define NP 100032
#define NE 800000
#define NG 256
#define NL 5
#define EPS 1e-5f

typedef __bf16 bf16x8 __attribute__((ext_vector_type(8)));
typedef float f32x4 __attribute__((ext_vector_type(4)));

__device__ __forceinline__ float bf2f(unsigned short u) {
  union { unsigned int i; float f; } x; x.i = ((unsigned int)u) << 16; return x.f;
}
__device__ __forceinline__ unsigned short f2bf(float f) {
  union { float f; unsigned int i; } x; x.f = f;
  unsigned int r = x.i + 0x7fffu + ((x.i >> 16) & 1u);
  return (unsigned short)(r >> 16);
}

// ---------------- init: A = bf16(atom_emb[x]) ----------------
__global__ __launch_bounds__(256) void init_h_k(const int* __restrict__ x,
                                                const float* __restrict__ atom_emb,
                                                unsigned short* __restrict__ A) {
  int i = blockIdx.x * 256 + threadIdx.x;   // NN*8 exactly
  int n = i >> 3, c0 = (i & 7) * 8;
  const float* p = atom_emb + (size_t)x[n] * 64 + c0;
  float4 v0 = *(const float4*)p;
  float4 v1 = *(const float4*)(p + 4);
  union { bf16x8 b; unsigned short u[8]; } o;
  o.u[0] = f2bf(v0.x); o.u[1] = f2bf(v0.y); o.u[2] = f2bf(v0.z); o.u[3] = f2bf(v0.w);
  o.u[4] = f2bf(v1.x); o.u[5] = f2bf(v1.y); o.u[6] = f2bf(v1.z); o.u[7] = f2bf(v1.w);
  *(bf16x8*)(A + (size_t)n * 64 + c0) = o.b;
}

// ---------------- weight transpose+convert: Wt[l][col][k] = bf16(W[l][k][col]) ----------------
__global__ __launch_bounds__(256) void wconv_k(const float* __restrict__ W1,
                                               const float* __restrict__ W2,
                                               unsigned short* __restrict__ Wt1,
                                               unsigned short* __restrict__ Wt2) {
  int i = blockIdx.x * 256 + threadIdx.x;
  const int S = NL * 128 * 64;   // 40960
  if (i < S) {
    int l = i / (128 * 64), r = i % (128 * 64);
    int c = r / 64, k = r % 64;
    Wt1[i] = f2bf(W1[(size_t)l * 64 * 128 + (size_t)k * 128 + c]);
  } else if (i < 2 * S) {
    int j = i - S;
    int l = j / (128 * 64), r = j % (128 * 64);
    int c = r / 128, k = r % 128;
    Wt2[j] = f2bf(W2[(size_t)l * 128 * 64 + (size_t)k * 64 + c]);
  }
}

// ---------------- CSR build ----------------
__global__ __launch_bounds__(256) void hist_k(const int* __restrict__ ei,
                                              int* __restrict__ cnt) {
  int e = blockIdx.x * 256 + threadIdx.x;
  if (e >= NE) return;
  atomicAdd(&cnt[ei[NE + e]], 1);
}

__global__ __launch_bounds__(256) void scan1_k(const int* __restrict__ cnt,
                                               int* __restrict__ rs,
                                               int* __restrict__ bsum) {
  __shared__ int sh[256];
  int t = threadIdx.x;
  int base = blockIdx.x * 1024 + t * 4;
  int v0 = 0, v1 = 0, v2 = 0, v3 = 0;
  if (base + 0 < NN) v0 = cnt[base + 0];
  if (base + 1 < NN) v1 = cnt[base + 1];
  if (base + 2 < NN) v2 = cnt[base + 2];
  if (base + 3 < NN) v3 = cnt[base + 3];
  int tsum = v0 + v1 + v2 + v3;
  sh[t] = tsum;
  __syncthreads();
  for (int off = 1; off < 256; off <<= 1) {
    int x = (t >= off) ? sh[t - off] : 0;
    __syncthreads();
    sh[t] += x;
    __syncthreads();
  }
  int excl = sh[t] - tsum;
  if (base + 0 < NN) rs[base + 0] = excl;
  if (base + 1 < NN) rs[base + 1] = excl + v0;
  if (base + 2 < NN) rs[base + 2] = excl + v0 + v1;
  if (base + 3 < NN) rs[base + 3] = excl + v0 + v1 + v2;
  if (t == 255) bsum[blockIdx.x] = sh[255];
}

__global__ void scan2_k(const int* __restrict__ bsum, int* __restrict__ bofs, int nb) {
  if (threadIdx.x == 0 && blockIdx.x == 0) {
    int run = 0;
    for (int i = 0; i < nb; ++i) { bofs[i] = run; run += bsum[i]; }
  }
}

__global__ __launch_bounds__(256) void scan3_k(int* __restrict__ rs,
                                               const int* __restrict__ bofs,
                                               int* __restrict__ cursor) {
  int i = blockIdx.x * 256 + threadIdx.x;
  if (i < NN) {
    int v = rs[i] + bofs[i >> 10];
    rs[i] = v;
    cursor[i] = v;
  }
  if (i == 0) rs[NN] = NE;
}

// XCD-banded scatter (keeps per-band epack slice XCD-local so stores merge)
__global__ __launch_bounds__(256) void scatter_k(const int* __restrict__ ei,
                                                 const int* __restrict__ eattr,
                                                 int* __restrict__ cursor,
                                                 int* __restrict__ epack) {
  int band = blockIdx.x & 7;
  int e = (blockIdx.x >> 3) * 256 + threadIdx.x;
  if (e >= NE) return;
  int d = ei[NE + e];
  if (d / 12500 != band) return;
  int slot = atomicAdd(&cursor[d], 1);
  epack[slot] = (ei[e] << 3) | eattr[e];
}

// ---------------- gather: B[w] = hsrc(w) + sum relu(hsrc(src)+bond[b]) ----------------
// hsrc(n) = MODE ? relu(A[n]*scl+shf) : A[n]; BN2-finalize of prev layer folded into prologue.
// 8-wide: lane = (es 0-7, cg 0-7); 8 edges in flight. Each wave owns 4 consecutive rows
// (amortizes prologue 4x). Bond rows padded to 68 f32 -> distinct bank offsets.
template <int MODE>
__global__ __launch_bounds__(256) void csr_aggr_k(const int* __restrict__ rowstart,
                                                  const int* __restrict__ epack,
                                                  const float* __restrict__ bond,
                                                  const unsigned short* __restrict__ A,
                                                  const float* __restrict__ stat2prev,
                                                  const float* __restrict__ g,
                                                  const float* __restrict__ be,
                                                  unsigned short* __restrict__ B) {
  __shared__ float bl[5][68];   // bond, padded rows
  __shared__ float scl64[64], shf64[64];
  int tid = threadIdx.x;
  for (int j = tid; j < 320; j += 256) bl[j >> 6][j & 63] = bond[j];
  if (MODE && tid < 64) {
    float s = 0.f, s2 = 0.f;
#pragma unroll
    for (int r = 0; r < 8; ++r) { s += stat2prev[r * 128 + tid]; s2 += stat2prev[r * 128 + 64 + tid]; }
    float mean = s * (1.f / NN);
    float var = fmaxf(s2 * (1.f / NN) - mean * mean, 0.f);
    float sc = g[tid] * rsqrtf(var + EPS);
    scl64[tid] = sc;
    shf64[tid] = be[tid] - mean * sc;
  }
  __syncthreads();

  int w = tid >> 6, lane = tid & 63;
  int es = lane >> 3, cg = lane & 7, c0 = cg * 8;
  float sc[8], sf[8];
  if (MODE) {
#pragma unroll
    for (int j = 0; j < 8; ++j) { sc[j] = scl64[c0 + j]; sf[j] = shf64[c0 + j]; }
  }
  int base16 = blockIdx.x * 16 + w * 4;   // 6250*16 == NN
#pragma unroll
  for (int r4 = 0; r4 < 4; ++r4) {
    int w0 = base16 + r4;
    int s = rowstart[w0], e = rowstart[w0 + 1];
    float acc[8];
#pragma unroll
    for (int j = 0; j < 8; ++j) acc[j] = 0.f;
    for (int base = s; base < e; base += 64) {
      int m = e - base; if (m > 64) m = 64;
      int pk = (lane < m) ? epack[base + lane] : 0;
      int iters = (m + 7) >> 3;
      for (int i = 0; i < iters; ++i) {
        int idx = i * 8 + es;
        int p = __shfl(pk, idx);
        if (idx < m) {
          union { bf16x8 b; unsigned short u[8]; } hv;
          hv.b = *(const bf16x8*)(A + (size_t)(p >> 3) * 64 + c0);
          const float* bp = &bl[p & 7][c0];
          float4 b0 = *(const float4*)(bp);
          float4 b1 = *(const float4*)(bp + 4);
          float bb[8] = {b0.x, b0.y, b0.z, b0.w, b1.x, b1.y, b1.z, b1.w};
#pragma unroll
          for (int j = 0; j < 8; ++j) {
            float v = bf2f(hv.u[j]);
            if (MODE) v = fmaxf(fmaf(v, sc[j], sf[j]), 0.f);
            acc[j] += fmaxf(v + bb[j], 0.f);
          }
        }
      }
    }
#pragma unroll
    for (int j = 0; j < 8; ++j) {
      acc[j] += __shfl_xor(acc[j], 8);
      acc[j] += __shfl_xor(acc[j], 16);
      acc[j] += __shfl_xor(acc[j], 32);
    }
    if (es == 0) {
      union { bf16x8 b; unsigned short u[8]; } rv, o;
      rv.b = *(const bf16x8*)(A + (size_t)w0 * 64 + c0);
#pragma unroll
      for (int j = 0; j < 8; ++j) {
        float r = bf2f(rv.u[j]);
        if (MODE) r = fmaxf(fmaf(r, sc[j], sf[j]), 0.f);
        o.u[j] = f2bf(acc[j] + r);
      }
      *(bf16x8*)(B + (size_t)w0 * 64 + c0) = o.b;
    }
  }
}

// ---------------- stat1 (MFMA): per-column sum/sumsq of y = B @ W1, y never stored ----------------
// Grid MUST be 256. 8-striped f32 atomics into stat1[8][256] (s at [r][c], s2 at [r][128+c]).
__global__ __launch_bounds__(256) void stat1_k(const unsigned short* __restrict__ B,
                                               const unsigned short* __restrict__ Wt1,
                                               float* __restrict__ stat1) {
  int tid = threadIdx.x;
  int w = tid >> 6, lane = tid & 63;
  int rlo = lane & 15, khi = lane >> 4;
  bf16x8 wf0[8], wf1[8];
#pragma unroll
  for (int ct = 0; ct < 8; ++ct) {
    const bf16x8* bp = (const bf16x8*)(Wt1 + (size_t)(ct * 16 + rlo) * 64 + khi * 8);
    wf0[ct] = bp[0];
    wf1[ct] = bp[4];
  }
  float s[8], s2[8];
#pragma unroll
  for (int ct = 0; ct < 8; ++ct) { s[ct] = 0.f; s2[ct] = 0.f; }
  union { bf16x8 b; uint4 u; } zz; zz.u = make_uint4(0, 0, 0, 0);
  for (int t = blockIdx.x * 4 + w; t < NP / 16; t += 1024) {
    int row = t * 16 + rlo;
    bf16x8 a0, a1;
    if (row < NN) {
      const bf16x8* ap = (const bf16x8*)(B + (size_t)row * 64 + khi * 8);
      a0 = ap[0]; a1 = ap[4];
    } else {
      a0 = zz.b; a1 = zz.b;
    }
#pragma unroll
    for (int ct = 0; ct < 8; ++ct) {
      f32x4 acc;
      acc[0] = 0.f; acc[1] = 0.f; acc[2] = 0.f; acc[3] = 0.f;
      acc = __builtin_amdgcn_mfma_f32_16x16x32_bf16(a0, wf0[ct], acc, 0, 0, 0);
      acc = __builtin_amdgcn_mfma_f32_16x16x32_bf16(a1, wf1[ct], acc, 0, 0, 0);
#pragma unroll
      for (int q = 0; q < 4; ++q) {
        s[ct] += acc[q];
        s2[ct] = fmaf(acc[q], acc[q], s2[ct]);
      }
    }
  }
#pragma unroll
  for (int ct = 0; ct < 8; ++ct) {
    s[ct] += __shfl_xor(s[ct], 16);  s[ct] += __shfl_xor(s[ct], 32);
    s2[ct] += __shfl_xor(s2[ct], 16); s2[ct] += __shfl_xor(s2[ct], 32);
  }
  if (khi == 0) {
    float* dst = stat1 + (blockIdx.x & 7) * 256;
#pragma unroll
    for (int ct = 0; ct < 8; ++ct) {
      atomicAdd(&dst[ct * 16 + rlo], s[ct]);
      atomicAdd(&dst[128 + ct * 16 + rlo], s2[ct]);
    }
  }
}

// ---------------- fused gemm1+BN1+relu+gemm2; BN1 finalize from stat1 in prologue ----------------
__global__ __launch_bounds__(256) void gemm12_k(const unsigned short* __restrict__ B,
                                                const unsigned short* __restrict__ Wt1,
                                                const unsigned short* __restrict__ Wt2,
                                                const float* __restrict__ stat1,
                                                const float* __restrict__ g1,
                                                const float* __restrict__ be1,
                                                const float* __restrict__ b2,
                                                unsigned short* __restrict__ z2b,
                                                float* __restrict__ stat2f) {
  __shared__ unsigned short Zs[64][136];   // z1 tile (bf16, post BN1+relu)
  __shared__ float sclS[128], shfS[128], sred[128];
  int tid = threadIdx.x;
  if (tid < 128) {
    float s = 0.f, s2 = 0.f;
#pragma unroll
    for (int r = 0; r < 8; ++r) { s += stat1[r * 256 + tid]; s2 += stat1[r * 256 + 128 + tid]; }
    float mean = s * (1.f / NN);
    float var = fmaxf(s2 * (1.f / NN) - mean * mean, 0.f);
    float sc = g1[tid] * rsqrtf(var + EPS);
    sclS[tid] = sc;
    shfS[tid] = be1[tid] - mean * sc;
    sred[tid] = 0.f;
  }
  __syncthreads();
  int w = tid >> 6, lane = tid & 63;
  int rlo = lane & 15, khi = lane >> 4;
  int row0 = blockIdx.x * 64 + w * 16;
  // phase 1: y = B @ W1 (bias cancels in BN), BN1+relu in-register (unrounded y)
  const bf16x8* ap = (const bf16x8*)(B + (size_t)(row0 + rlo) * 64 + khi * 8);
  bf16x8 a0 = ap[0], a1 = ap[4];
#pragma unroll
  for (int ct = 0; ct < 8; ++ct) {
    const bf16x8* bp = (const bf16x8*)(Wt1 + (size_t)(ct * 16 + rlo) * 64 + khi * 8);
    f32x4 acc;
    acc[0] = 0.f; acc[1] = 0.f; acc[2] = 0.f; acc[3] = 0.f;
    acc = __builtin_amdgcn_mfma_f32_16x16x32_bf16(a0, bp[0], acc, 0, 0, 0);
    acc = __builtin_amdgcn_mfma_f32_16x16x32_bf16(a1, bp[4], acc, 0, 0, 0);
    int c = ct * 16 + rlo;
    float sc = sclS[c], sf = shfS[c];
#pragma unroll
    for (int q = 0; q < 4; ++q)
      Zs[w * 16 + khi * 4 + q][c] = f2bf(fmaxf(fmaf(acc[q], sc, sf), 0.f));
  }
  // phase 2 A-frags: rows w*16.. owned by this wave -> intra-wave LDS dep only
  bf16x8 af0 = *(const bf16x8*)&Zs[w * 16 + rlo][khi * 8];
  bf16x8 af1 = *(const bf16x8*)&Zs[w * 16 + rlo][32 + khi * 8];
  bf16x8 af2 = *(const bf16x8*)&Zs[w * 16 + rlo][64 + khi * 8];
  bf16x8 af3 = *(const bf16x8*)&Zs[w * 16 + rlo][96 + khi * 8];
  __syncthreads();   // all reads done before Zs reused as z2 staging
  f32x4 acc2[4];
#pragma unroll
  for (int ct = 0; ct < 4; ++ct) { acc2[ct][0] = 0.f; acc2[ct][1] = 0.f; acc2[ct][2] = 0.f; acc2[ct][3] = 0.f; }
#pragma unroll
  for (int ct = 0; ct < 4; ++ct) {
    const bf16x8* bp = (const bf16x8*)(Wt2 + (size_t)(ct * 16 + rlo) * 128 + khi * 8);
    acc2[ct] = __builtin_amdgcn_mfma_f32_16x16x32_bf16(af0, bp[0], acc2[ct], 0, 0, 0);
    acc2[ct] = __builtin_amdgcn_mfma_f32_16x16x32_bf16(af1, bp[4], acc2[ct], 0, 0, 0);
    acc2[ct] = __builtin_amdgcn_mfma_f32_16x16x32_bf16(af2, bp[8], acc2[ct], 0, 0, 0);
    acc2[ct] = __builtin_amdgcn_mfma_f32_16x16x32_bf16(af3, bp[12], acc2[ct], 0, 0, 0);
  }
  unsigned short (*Z2)[72] = (unsigned short(*)[72])Zs;
#pragma unroll
  for (int ct = 0; ct < 4; ++ct) {
    int c = ct * 16 + rlo;
    float bs = b2[c];
    float s = 0.f, s2 = 0.f;
#pragma unroll
    for (int q = 0; q < 4; ++q) {
      int brow = w * 16 + khi * 4 + q;
      float v = acc2[ct][q] + bs;
      unsigned short ub = f2bf(v);
      Z2[brow][c] = ub;
      float vf = bf2f(ub);
      if (blockIdx.x * 64 + brow < NN) { s += vf; s2 += vf * vf; }
    }
    atomicAdd(&sred[c], s);
    atomicAdd(&sred[64 + c], s2);
  }
  __syncthreads();
#pragma unroll
  for (int pass = 0; pass < 2; ++pass) {
    int orow = pass * 32 + (tid >> 3), oc0 = (tid & 7) * 8;
    *(bf16x8*)(z2b + (size_t)(blockIdx.x * 64 + orow) * 64 + oc0) =
        *(const bf16x8*)&Z2[orow][oc0];
  }
  if (tid < 128) atomicAdd(&stat2f[(blockIdx.x & 7) * 128 + tid], sred[tid]);
}

// ---------------- final BN apply (no relu) -> f32 h output; BN2 finalize in prologue ----------------
__global__ __launch_bounds__(256) void bn_final_k(const unsigned short* __restrict__ A,
                                                  const float* __restrict__ stat2f,
                                                  const float* __restrict__ g,
                                                  const float* __restrict__ be,
                                                  float* __restrict__ hf) {
  __shared__ float scl[64], shf[64];
  int tid = threadIdx.x;
  if (tid < 64) {
    float s = 0.f, s2 = 0.f;
#pragma unroll
    for (int r = 0; r < 8; ++r) { s += stat2f[r * 128 + tid]; s2 += stat2f[r * 128 + 64 + tid]; }
    float mean = s * (1.f / NN);
    float var = fmaxf(s2 * (1.f / NN) - mean * mean, 0.f);
    float sc = g[tid] * rsqrtf(var + EPS);
    scl[tid] = sc;
    shf[tid] = be[tid] - mean * sc;
  }
  __syncthreads();
  int i = blockIdx.x * 256 + tid;   // NN*8 exactly
  int n = i >> 3, c0 = (i & 7) * 8;
  union { bf16x8 b; unsigned short u[8]; } raw;
  raw.b = *(const bf16x8*)(A + (size_t)n * 64 + c0);
  float v[8];
#pragma unroll
  for (int j = 0; j < 8; ++j) v[j] = fmaf(bf2f(raw.u[j]), scl[c0 + j], shf[c0 + j]);
  float* p = hf + (size_t)n * 64 + c0;
  *(float4*)(p)     = make_float4(v[0], v[1], v[2], v[3]);
  *(float4*)(p + 4) = make_float4(v[4], v[5], v[6], v[7]);
}

// ---------------- pool: xpool[batch[n]] += h[n]  (batch sorted) ----------------
__global__ __launch_bounds__(256) void pool_k(const float* __restrict__ h,
                                              const int* __restrict__ batch,
                                              float* __restrict__ xpool) {
  int n0 = blockIdx.x * 16;
  int tid = threadIdx.x;
  int r = tid >> 4, c4 = tid & 15;
  int n = n0 + r;
  float4 v = *(const float4*)(h + (size_t)n * 64 + c4 * 4);
  __shared__ int gfirst, gsame;
  __shared__ float red[16][64];
  if (tid == 0) {
    gfirst = batch[n0];
    gsame = (batch[n0] == batch[n0 + 15]) ? 1 : 0;
  }
  *(float4*)&red[r][c4 * 4] = v;
  __syncthreads();
  if (gsame) {
#pragma unroll
    for (int off = 8; off >= 1; off >>= 1) {
      if (r < off) {
        float4 a = *(float4*)&red[r][c4 * 4];
        float4 b = *(float4*)&red[r + off][c4 * 4];
        *(float4*)&red[r][c4 * 4] = make_float4(a.x + b.x, a.y + b.y, a.z + b.z, a.w + b.w);
      }
      __syncthreads();
    }
    if (r == 0) {
      float* p = xpool + (size_t)gfirst * 64 + c4 * 4;
      float4 a = *(float4*)&red[0][c4 * 4];
      atomicAdd(p + 0, a.x); atomicAdd(p + 1, a.y);
      atomicAdd(p + 2, a.z); atomicAdd(p + 3, a.w);
    }
  } else {
    int g = batch[n];
    float* p = xpool + (size_t)g * 64 + c4 * 4;
    atomicAdd(p + 0, v.x); atomicAdd(p + 1, v.y);
    atomicAdd(p + 2, v.z); atomicAdd(p + 3, v.w);
  }
}

extern "C" void kernel_launch(void* const* d_in, const int* in_sizes, int n_in,
                              void* d_out, int out_size, void* d_ws, size_t ws_size,
                              hipStream_t stream) {
  const int* batch = (const int*)d_in[0];
  const int* x = (const int*)d_in[1];
  const int* ei = (const int*)d_in[2];
  const int* eattr = (const int*)d_in[3];
  const float* atom_emb = (const float*)d_in[4];
  const float* bond_emb = (const float*)d_in[5];
  const float* W1 = (const float*)d_in[6];
  const float* g1 = (const float*)d_in[8];
  const float* be1 = (const float*)d_in[9];
  const float* W2 = (const float*)d_in[10];
  const float* b2 = (const float*)d_in[11];
  const float* gbn = (const float*)d_in[12];
  const float* bbn = (const float*)d_in[13];

  float* out = (float*)d_out;
  float* xpool = out;               // 256*64
  float* hf = out + NG * 64;        // final f32 h lives directly in output

  char* ws = (char*)d_ws;
  unsigned short* A   = (unsigned short*)(ws);                      // NP*64 bf16 (h / z2)
  unsigned short* B   = (unsigned short*)(ws + 12804096);           // NP*64 bf16 (z = h+aggr)
  float* sbuf         = (float*)(ws + 25608192);                    // 5*3072 f32 = 61440 B
  unsigned short* Wt1 = (unsigned short*)(ws + 25669632);           // 5*128*64 bf16
  unsigned short* Wt2 = (unsigned short*)(ws + 25751552);           // 5*64*128 bf16
  int* rowstart       = (int*)(ws + 25833472);                      // NN+1 ints
  int* epack          = (int*)(ws + 26233600);                      // NE ints -> ends ~29.4MB
  // CSR build temporaries alias B region (dead until first csr_aggr)
  int* cnt    = (int*)(ws + 12804096);
  int* cursor = (int*)(ws + 12804096 + 1048576);
  int* bsum   = (int*)(ws + 12804096 + 2097152);
  int* bofs   = bsum + 128;

  init_h_k<<<NN * 8 / 256, 256, 0, stream>>>(x, atom_emb, A);
  wconv_k<<<(2 * NL * 128 * 64 + 255) / 256, 256, 0, stream>>>(W1, W2, Wt1, Wt2);

  // ---- CSR build (edge structure shared by all layers) ----
  hipMemsetAsync(cnt, 0, (size_t)NN * 4, stream);
  hist_k<<<(NE + 255) / 256, 256, 0, stream>>>(ei, cnt);
  scan1_k<<<98, 256, 0, stream>>>(cnt, rowstart, bsum);
  scan2_k<<<1, 64, 0, stream>>>(bsum, bofs, 98);
  scan3_k<<<(NN + 255) / 256, 256, 0, stream>>>(rowstart, bofs, cursor);
  scatter_k<<<8 * ((NE + 255) / 256), 256, 0, stream>>>(ei, eattr, cursor, epack);

  hipMemsetAsync(sbuf, 0, 61440, stream);
  for (int l = 0; l < NL; ++l) {
    float* stat1 = sbuf + (size_t)l * 3072;
    float* stat2 = sbuf + (size_t)l * 3072 + 2048;
    float* stat2p = sbuf + (size_t)(l - 1) * 3072 + 2048;
    if (l == 0)
      csr_aggr_k<0><<<NN / 16, 256, 0, stream>>>(rowstart, epack, bond_emb, A,
                                                 sbuf, gbn, bbn, B);
    else
      csr_aggr_k<1><<<NN / 16, 256, 0, stream>>>(rowstart, epack, bond_emb, A,
                                                 stat2p, gbn + (size_t)(l - 1) * 64,
                                                 bbn + (size_t)(l - 1) * 64, B);
    stat1_k<<<256, 256, 0, stream>>>(B, Wt1 + (size_t)l * 128 * 64, stat1);
    gemm12_k<<<NP / 64, 256, 0, stream>>>(B, Wt1 + (size_t)l * 128 * 64,
                                          Wt2 + (size_t)l * 64 * 128,
                                          stat1, g1 + (size_t)l * 128, be1 + (size_t)l * 128,
                                          b2 + (size_t)l * 64, A, stat2);
  }

  bn_final_k<<<NN * 8 / 256, 256, 0, stream>>>(A, sbuf + (size_t)(NL - 1) * 3072 + 2048,
                                               gbn + (size_t)(NL - 1) * 64,
                                               bbn + (size_t)(NL - 1) * 64, hf);

  hipMemsetAsync(xpool, 0, (size_t)NG * 64 * 4, stream);
  pool_k<<<NN / 16, 256, 0, stream>>>(hf, batch, xpool);
}

// Round 9
// 506.580 us; speedup vs baseline: 5.6422x; 1.1852x over previous
//
#include <hip/hip_runtime.h>
#include <cstdint>
#include <cstddef>

#define NN 100000
#define NP 100032
#define NE 800000
#define NG 256
#define NL 5
#define EPS 1e-5f

typedef __bf16 bf16x8 __attribute__((ext_vector_type(8)));
typedef float f32x4 __attribute__((ext_vector_type(4)));

__device__ __forceinline__ float bf2f(unsigned short u) {
  union { unsigned int i; float f; } x; x.i = ((unsigned int)u) << 16; return x.f;
}
__device__ __forceinline__ unsigned short f2bf(float f) {
  union { float f; unsigned int i; } x; x.f = f;
  unsigned int r = x.i + 0x7fffu + ((x.i >> 16) & 1u);
  return (unsigned short)(r >> 16);
}

// ---------------- fused prep: A = bf16(atom_emb[x]) | weight transpose | cnt zero ----------------
__global__ __launch_bounds__(256) void prep_k(const int* __restrict__ x,
                                              const float* __restrict__ atom_emb,
                                              unsigned short* __restrict__ A,
                                              const float* __restrict__ W1,
                                              const float* __restrict__ W2,
                                              unsigned short* __restrict__ Wt1,
                                              unsigned short* __restrict__ Wt2,
                                              int* __restrict__ cnt) {
  int b = blockIdx.x, t = threadIdx.x;
  if (b < 3125) {                       // init h: NN*8 threads
    int i = b * 256 + t;
    int n = i >> 3, c0 = (i & 7) * 8;
    const float* p = atom_emb + (size_t)x[n] * 64 + c0;
    float4 v0 = *(const float4*)p;
    float4 v1 = *(const float4*)(p + 4);
    union { bf16x8 b8; unsigned short u[8]; } o;
    o.u[0] = f2bf(v0.x); o.u[1] = f2bf(v0.y); o.u[2] = f2bf(v0.z); o.u[3] = f2bf(v0.w);
    o.u[4] = f2bf(v1.x); o.u[5] = f2bf(v1.y); o.u[6] = f2bf(v1.z); o.u[7] = f2bf(v1.w);
    *(bf16x8*)(A + (size_t)n * 64 + c0) = o.b8;
  } else if (b < 3445) {                // wconv: 81920 threads (320 blocks exactly)
    int i = (b - 3125) * 256 + t;
    const int S = NL * 128 * 64;        // 40960
    if (i < S) {
      int l = i / (128 * 64), r = i % (128 * 64);
      int c = r / 64, k = r % 64;
      Wt1[i] = f2bf(W1[(size_t)l * 64 * 128 + (size_t)k * 128 + c]);
    } else {
      int j = i - S;
      int l = j / (128 * 64), r = j % (128 * 64);
      int c = r / 128, k = r % 128;
      Wt2[j] = f2bf(W2[(size_t)l * 128 * 64 + (size_t)k * 64 + c]);
    }
  } else {                              // zero cnt
    int i = (b - 3445) * 256 + t;
    if (i < NN) cnt[i] = 0;
  }
}

// ---------------- CSR build ----------------
__global__ __launch_bounds__(256) void hist_k(const int* __restrict__ ei,
                                              int* __restrict__ cnt) {
  int e = blockIdx.x * 256 + threadIdx.x;
  if (e >= NE) return;
  atomicAdd(&cnt[ei[NE + e]], 1);
}

__global__ __launch_bounds__(256) void scan1_k(const int* __restrict__ cnt,
                                               int* __restrict__ rs,
                                               int* __restrict__ bsum) {
  __shared__ int sh[256];
  int t = threadIdx.x;
  int base = blockIdx.x * 1024 + t * 4;
  int v0 = 0, v1 = 0, v2 = 0, v3 = 0;
  if (base + 0 < NN) v0 = cnt[base + 0];
  if (base + 1 < NN) v1 = cnt[base + 1];
  if (base + 2 < NN) v2 = cnt[base + 2];
  if (base + 3 < NN) v3 = cnt[base + 3];
  int tsum = v0 + v1 + v2 + v3;
  sh[t] = tsum;
  __syncthreads();
  for (int off = 1; off < 256; off <<= 1) {
    int x = (t >= off) ? sh[t - off] : 0;
    __syncthreads();
    sh[t] += x;
    __syncthreads();
  }
  int excl = sh[t] - tsum;
  if (base + 0 < NN) rs[base + 0] = excl;
  if (base + 1 < NN) rs[base + 1] = excl + v0;
  if (base + 2 < NN) rs[base + 2] = excl + v0 + v1;
  if (base + 3 < NN) rs[base + 3] = excl + v0 + v1 + v2;
  if (t == 255) bsum[blockIdx.x] = sh[255];
}

// scan3 with block-sum prefix folded in (chunk = blockIdx>>2 is block-uniform)
__global__ __launch_bounds__(256) void scan3_k(int* __restrict__ rs,
                                               const int* __restrict__ bsum,
                                               int* __restrict__ cursor) {
  int i = blockIdx.x * 256 + threadIdx.x;
  int chunk = blockIdx.x >> 2;
  int boff = 0;
  for (int j = 0; j < chunk; ++j) boff += bsum[j];
  if (i < NN) {
    int v = rs[i] + boff;
    rs[i] = v;
    cursor[i] = v;
  }
  if (i == 0) rs[NN] = NE;
}

// XCD-banded scatter (keeps per-band epack slice XCD-local so stores merge)
__global__ __launch_bounds__(256) void scatter_k(const int* __restrict__ ei,
                                                 const int* __restrict__ eattr,
                                                 int* __restrict__ cursor,
                                                 int* __restrict__ epack) {
  int band = blockIdx.x & 7;
  int e = (blockIdx.x >> 3) * 256 + threadIdx.x;
  if (e >= NE) return;
  int d = ei[NE + e];
  if (d / 12500 != band) return;
  int slot = atomicAdd(&cursor[d], 1);
  epack[slot] = (ei[e] << 3) | eattr[e];
}

// ---------------- gather: B[row] = hsrc(row) + sum relu(hsrc(src)+bond[b]) ----------------
// hsrc(n) = MODE ? relu(A[n]*scl+shf) : A[n]; BN2-finalize of prev layer in prologue.
// Subgroup-per-row: lane = (sg 0-7 = row, ch 0-7 = 8 channels). No shuffles, no reduce.
template <int MODE>
__global__ __launch_bounds__(256) void csr_aggr_k(const int* __restrict__ rowstart,
                                                  const int* __restrict__ epack,
                                                  const float* __restrict__ bond,
                                                  const unsigned short* __restrict__ A,
                                                  const float* __restrict__ stat2prev,
                                                  const float* __restrict__ g,
                                                  const float* __restrict__ be,
                                                  unsigned short* __restrict__ B) {
  __shared__ float bl[5][68];   // bond, padded rows
  __shared__ float scl64[64], shf64[64];
  int tid = threadIdx.x;
  for (int j = tid; j < 320; j += 256) bl[j >> 6][j & 63] = bond[j];
  if (MODE && tid < 64) {
    float s = 0.f, s2 = 0.f;
#pragma unroll
    for (int r = 0; r < 8; ++r) { s += stat2prev[r * 128 + tid]; s2 += stat2prev[r * 128 + 64 + tid]; }
    float mean = s * (1.f / NN);
    float var = fmaxf(s2 * (1.f / NN) - mean * mean, 0.f);
    float sc = g[tid] * rsqrtf(var + EPS);
    scl64[tid] = sc;
    shf64[tid] = be[tid] - mean * sc;
  }
  __syncthreads();

  int lane = tid & 63;
  int sg = lane >> 3, ch = lane & 7, c0 = ch * 8;
  int row = blockIdx.x * 32 + (tid >> 6) * 8 + sg;   // 3125 blocks * 32 rows == NN
  float sc[8], sf[8];
  if (MODE) {
#pragma unroll
    for (int j = 0; j < 8; ++j) { sc[j] = scl64[c0 + j]; sf[j] = shf64[c0 + j]; }
  }
  int s = rowstart[row], e = rowstart[row + 1];
  float acc[8];
#pragma unroll
  for (int j = 0; j < 8; ++j) acc[j] = 0.f;
  int i = s;
  for (; i + 2 <= e; i += 2) {
    int p0 = epack[i], p1 = epack[i + 1];
    union { bf16x8 b; unsigned short u[8]; } h0, h1;
    h0.b = *(const bf16x8*)(A + (size_t)(p0 >> 3) * 64 + c0);
    h1.b = *(const bf16x8*)(A + (size_t)(p1 >> 3) * 64 + c0);
    const float* bp0 = &bl[p0 & 7][c0];
    const float* bp1 = &bl[p1 & 7][c0];
    float4 a0 = *(const float4*)(bp0), a1 = *(const float4*)(bp0 + 4);
    float4 d0 = *(const float4*)(bp1), d1 = *(const float4*)(bp1 + 4);
    float bb0[8] = {a0.x, a0.y, a0.z, a0.w, a1.x, a1.y, a1.z, a1.w};
    float bb1[8] = {d0.x, d0.y, d0.z, d0.w, d1.x, d1.y, d1.z, d1.w};
#pragma unroll
    for (int j = 0; j < 8; ++j) {
      float v0 = bf2f(h0.u[j]);
      float v1 = bf2f(h1.u[j]);
      if (MODE) {
        v0 = fmaxf(fmaf(v0, sc[j], sf[j]), 0.f);
        v1 = fmaxf(fmaf(v1, sc[j], sf[j]), 0.f);
      }
      acc[j] += fmaxf(v0 + bb0[j], 0.f);
      acc[j] += fmaxf(v1 + bb1[j], 0.f);
    }
  }
  if (i < e) {
    int p0 = epack[i];
    union { bf16x8 b; unsigned short u[8]; } h0;
    h0.b = *(const bf16x8*)(A + (size_t)(p0 >> 3) * 64 + c0);
    const float* bp0 = &bl[p0 & 7][c0];
    float4 a0 = *(const float4*)(bp0), a1 = *(const float4*)(bp0 + 4);
    float bb0[8] = {a0.x, a0.y, a0.z, a0.w, a1.x, a1.y, a1.z, a1.w};
#pragma unroll
    for (int j = 0; j < 8; ++j) {
      float v0 = bf2f(h0.u[j]);
      if (MODE) v0 = fmaxf(fmaf(v0, sc[j], sf[j]), 0.f);
      acc[j] += fmaxf(v0 + bb0[j], 0.f);
    }
  }
  union { bf16x8 b; unsigned short u[8]; } rv, o;
  rv.b = *(const bf16x8*)(A + (size_t)row * 64 + c0);
#pragma unroll
  for (int j = 0; j < 8; ++j) {
    float r = bf2f(rv.u[j]);
    if (MODE) r = fmaxf(fmaf(r, sc[j], sf[j]), 0.f);
    o.u[j] = f2bf(acc[j] + r);
  }
  *(bf16x8*)(B + (size_t)row * 64 + c0) = o.b;
}

// ---------------- stat1 (MFMA): per-column sum/sumsq of y = B @ W1, y never stored ----------------
// Grid MUST be 256. 8-striped f32 atomics into stat1[8][256].
__global__ __launch_bounds__(256) void stat1_k(const unsigned short* __restrict__ B,
                                               const unsigned short* __restrict__ Wt1,
                                               float* __restrict__ stat1) {
  int tid = threadIdx.x;
  int w = tid >> 6, lane = tid & 63;
  int rlo = lane & 15, khi = lane >> 4;
  bf16x8 wf0[8], wf1[8];
#pragma unroll
  for (int ct = 0; ct < 8; ++ct) {
    const bf16x8* bp = (const bf16x8*)(Wt1 + (size_t)(ct * 16 + rlo) * 64 + khi * 8);
    wf0[ct] = bp[0];
    wf1[ct] = bp[4];
  }
  float s[8], s2[8];
#pragma unroll
  for (int ct = 0; ct < 8; ++ct) { s[ct] = 0.f; s2[ct] = 0.f; }
  union { bf16x8 b; uint4 u; } zz; zz.u = make_uint4(0, 0, 0, 0);
  for (int t = blockIdx.x * 4 + w; t < NP / 16; t += 1024) {
    int row = t * 16 + rlo;
    bf16x8 a0, a1;
    if (row < NN) {
      const bf16x8* ap = (const bf16x8*)(B + (size_t)row * 64 + khi * 8);
      a0 = ap[0]; a1 = ap[4];
    } else {
      a0 = zz.b; a1 = zz.b;
    }
#pragma unroll
    for (int ct = 0; ct < 8; ++ct) {
      f32x4 acc;
      acc[0] = 0.f; acc[1] = 0.f; acc[2] = 0.f; acc[3] = 0.f;
      acc = __builtin_amdgcn_mfma_f32_16x16x32_bf16(a0, wf0[ct], acc, 0, 0, 0);
      acc = __builtin_amdgcn_mfma_f32_16x16x32_bf16(a1, wf1[ct], acc, 0, 0, 0);
#pragma unroll
      for (int q = 0; q < 4; ++q) {
        s[ct] += acc[q];
        s2[ct] = fmaf(acc[q], acc[q], s2[ct]);
      }
    }
  }
#pragma unroll
  for (int ct = 0; ct < 8; ++ct) {
    s[ct] += __shfl_xor(s[ct], 16);  s[ct] += __shfl_xor(s[ct], 32);
    s2[ct] += __shfl_xor(s2[ct], 16); s2[ct] += __shfl_xor(s2[ct], 32);
  }
  if (khi == 0) {
    float* dst = stat1 + (blockIdx.x & 7) * 256;
#pragma unroll
    for (int ct = 0; ct < 8; ++ct) {
      atomicAdd(&dst[ct * 16 + rlo], s[ct]);
      atomicAdd(&dst[128 + ct * 16 + rlo], s2[ct]);
    }
  }
}

// ---------------- fused gemm1+BN1+relu+gemm2; BN1 finalize from stat1 in prologue ----------------
__global__ __launch_bounds__(256) void gemm12_k(const unsigned short* __restrict__ B,
                                                const unsigned short* __restrict__ Wt1,
                                                const unsigned short* __restrict__ Wt2,
                                                const float* __restrict__ stat1,
                                                const float* __restrict__ g1,
                                                const float* __restrict__ be1,
                                                const float* __restrict__ b2,
                                                unsigned short* __restrict__ z2b,
                                                float* __restrict__ stat2f) {
  __shared__ unsigned short Zs[64][136];   // z1 tile (bf16, post BN1+relu)
  __shared__ float sclS[128], shfS[128], sred[128];
  int tid = threadIdx.x;
  if (tid < 128) {
    float s = 0.f, s2 = 0.f;
#pragma unroll
    for (int r = 0; r < 8; ++r) { s += stat1[r * 256 + tid]; s2 += stat1[r * 256 + 128 + tid]; }
    float mean = s * (1.f / NN);
    float var = fmaxf(s2 * (1.f / NN) - mean * mean, 0.f);
    float sc = g1[tid] * rsqrtf(var + EPS);
    sclS[tid] = sc;
    shfS[tid] = be1[tid] - mean * sc;
    sred[tid] = 0.f;
  }
  __syncthreads();
  int w = tid >> 6, lane = tid & 63;
  int rlo = lane & 15, khi = lane >> 4;
  int row0 = blockIdx.x * 64 + w * 16;
  const bf16x8* ap = (const bf16x8*)(B + (size_t)(row0 + rlo) * 64 + khi * 8);
  bf16x8 a0 = ap[0], a1 = ap[4];
#pragma unroll
  for (int ct = 0; ct < 8; ++ct) {
    const bf16x8* bp = (const bf16x8*)(Wt1 + (size_t)(ct * 16 + rlo) * 64 + khi * 8);
    f32x4 acc;
    acc[0] = 0.f; acc[1] = 0.f; acc[2] = 0.f; acc[3] = 0.f;
    acc = __builtin_amdgcn_mfma_f32_16x16x32_bf16(a0, bp[0], acc, 0, 0, 0);
    acc = __builtin_amdgcn_mfma_f32_16x16x32_bf16(a1, bp[4], acc, 0, 0, 0);
    int c = ct * 16 + rlo;
    float sc = sclS[c], sf = shfS[c];
#pragma unroll
    for (int q = 0; q < 4; ++q)
      Zs[w * 16 + khi * 4 + q][c] = f2bf(fmaxf(fmaf(acc[q], sc, sf), 0.f));
  }
  bf16x8 af0 = *(const bf16x8*)&Zs[w * 16 + rlo][khi * 8];
  bf16x8 af1 = *(const bf16x8*)&Zs[w * 16 + rlo][32 + khi * 8];
  bf16x8 af2 = *(const bf16x8*)&Zs[w * 16 + rlo][64 + khi * 8];
  bf16x8 af3 = *(const bf16x8*)&Zs[w * 16 + rlo][96 + khi * 8];
  __syncthreads();   // all reads done before Zs reused as z2 staging
  f32x4 acc2[4];
#pragma unroll
  for (int ct = 0; ct < 4; ++ct) { acc2[ct][0] = 0.f; acc2[ct][1] = 0.f; acc2[ct][2] = 0.f; acc2[ct][3] = 0.f; }
#pragma unroll
  for (int ct = 0; ct < 4; ++ct) {
    const bf16x8* bp = (const bf16x8*)(Wt2 + (size_t)(ct * 16 + rlo) * 128 + khi * 8);
    acc2[ct] = __builtin_amdgcn_mfma_f32_16x16x32_bf16(af0, bp[0], acc2[ct], 0, 0, 0);
    acc2[ct] = __builtin_amdgcn_mfma_f32_16x16x32_bf16(af1, bp[4], acc2[ct], 0, 0, 0);
    acc2[ct] = __builtin_amdgcn_mfma_f32_16x16x32_bf16(af2, bp[8], acc2[ct], 0, 0, 0);
    acc2[ct] = __builtin_amdgcn_mfma_f32_16x16x32_bf16(af3, bp[12], acc2[ct], 0, 0, 0);
  }
  unsigned short (*Z2)[72] = (unsigned short(*)[72])Zs;
#pragma unroll
  for (int ct = 0; ct < 4; ++ct) {
    int c = ct * 16 + rlo;
    float bs = b2[c];
    float s = 0.f, s2 = 0.f;
#pragma unroll
    for (int q = 0; q < 4; ++q) {
      int brow = w * 16 + khi * 4 + q;
      float v = acc2[ct][q] + bs;
      unsigned short ub = f2bf(v);
      Z2[brow][c] = ub;
      float vf = bf2f(ub);
      if (blockIdx.x * 64 + brow < NN) { s += vf; s2 += vf * vf; }
    }
    atomicAdd(&sred[c], s);
    atomicAdd(&sred[64 + c], s2);
  }
  __syncthreads();
#pragma unroll
  for (int pass = 0; pass < 2; ++pass) {
    int orow = pass * 32 + (tid >> 3), oc0 = (tid & 7) * 8;
    *(bf16x8*)(z2b + (size_t)(blockIdx.x * 64 + orow) * 64 + oc0) =
        *(const bf16x8*)&Z2[orow][oc0];
  }
  if (tid < 128) atomicAdd(&stat2f[(blockIdx.x & 7) * 128 + tid], sred[tid]);
}

// ---------------- fused final: BN2 apply (no relu) -> f32 h output + pool ----------------
__global__ __launch_bounds__(256) void final_k(const unsigned short* __restrict__ A,
                                               const float* __restrict__ stat2f,
                                               const float* __restrict__ g,
                                               const float* __restrict__ be,
                                               const int* __restrict__ batch,
                                               float* __restrict__ hf,
                                               float* __restrict__ xpool) {
  __shared__ float scl[64], shf[64];
  __shared__ float red[16][64];
  __shared__ int gfirst, gsame;
  int tid = threadIdx.x;
  if (tid < 64) {
    float s = 0.f, s2 = 0.f;
#pragma unroll
    for (int r = 0; r < 8; ++r) { s += stat2f[r * 128 + tid]; s2 += stat2f[r * 128 + 64 + tid]; }
    float mean = s * (1.f / NN);
    float var = fmaxf(s2 * (1.f / NN) - mean * mean, 0.f);
    float sc = g[tid] * rsqrtf(var + EPS);
    scl[tid] = sc;
    shf[tid] = be[tid] - mean * sc;
  }
  int n0 = blockIdx.x * 16;   // 6250 blocks * 16 rows == NN
  if (tid == 0) {
    gfirst = batch[n0];
    gsame = (batch[n0] == batch[n0 + 15]) ? 1 : 0;
  }
  __syncthreads();
  int r = tid >> 4, c4 = tid & 15;
  int n = n0 + r;
  ushort4 raw = *(const ushort4*)(A + (size_t)n * 64 + c4 * 4);
  int cb = c4 * 4;
  float4 v;
  v.x = fmaf(bf2f(raw.x), scl[cb + 0], shf[cb + 0]);
  v.y = fmaf(bf2f(raw.y), scl[cb + 1], shf[cb + 1]);
  v.z = fmaf(bf2f(raw.z), scl[cb + 2], shf[cb + 2]);
  v.w = fmaf(bf2f(raw.w), scl[cb + 3], shf[cb + 3]);
  *(float4*)(hf + (size_t)n * 64 + cb) = v;
  *(float4*)&red[r][cb] = v;
  __syncthreads();
  if (gsame) {
#pragma unroll
    for (int off = 8; off >= 1; off >>= 1) {
      if (r < off) {
        float4 a = *(float4*)&red[r][cb];
        float4 b = *(float4*)&red[r + off][cb];
        *(float4*)&red[r][cb] = make_float4(a.x + b.x, a.y + b.y, a.z + b.z, a.w + b.w);
      }
      __syncthreads();
    }
    if (r == 0) {
      float* p = xpool + (size_t)gfirst * 64 + cb;
      float4 a = *(float4*)&red[0][cb];
      atomicAdd(p + 0, a.x); atomicAdd(p + 1, a.y);
      atomicAdd(p + 2, a.z); atomicAdd(p + 3, a.w);
    }
  } else {
    int gg = batch[n];
    float* p = xpool + (size_t)gg * 64 + cb;
    atomicAdd(p + 0, v.x); atomicAdd(p + 1, v.y);
    atomicAdd(p + 2, v.z); atomicAdd(p + 3, v.w);
  }
}

extern "C" void kernel_launch(void* const* d_in, const int* in_sizes, int n_in,
                              void* d_out, int out_size, void* d_ws, size_t ws_size,
                              hipStream_t stream) {
  const int* batch = (const int*)d_in[0];
  const int* x = (const int*)d_in[1];
  const int* ei = (const int*)d_in[2];
  const int* eattr = (const int*)d_in[3];
  const float* atom_emb = (const float*)d_in[4];
  const float* bond_emb = (const float*)d_in[5];
  const float* W1 = (const float*)d_in[6];
  const float* g1 = (const float*)d_in[8];
  const float* be1 = (const float*)d_in[9];
  const float* W2 = (const float*)d_in[10];
  const float* b2 = (const float*)d_in[11];
  const float* gbn = (const float*)d_in[12];
  const float* bbn = (const float*)d_in[13];

  float* out = (float*)d_out;
  float* xpool = out;               // 256*64
  float* hf = out + NG * 64;        // final f32 h lives directly in output

  char* ws = (char*)d_ws;
  unsigned short* A   = (unsigned short*)(ws);                      // NP*64 bf16 (h / z2)
  unsigned short* B   = (unsigned short*)(ws + 12804096);           // NP*64 bf16 (z = h+aggr)
  float* sbuf         = (float*)(ws + 25608192);                    // 5*3072 f32 = 61440 B
  unsigned short* Wt1 = (unsigned short*)(ws + 25669632);           // 5*128*64 bf16
  unsigned short* Wt2 = (unsigned short*)(ws + 25751552);           // 5*64*128 bf16
  int* rowstart       = (int*)(ws + 25833472);                      // NN+1 ints
  int* epack          = (int*)(ws + 26233600);                      // NE ints -> ends ~29.4MB
  // CSR build temporaries alias B region (dead until first csr_aggr)
  int* cnt    = (int*)(ws + 12804096);
  int* cursor = (int*)(ws + 12804096 + 1048576);
  int* bsum   = (int*)(ws + 12804096 + 2097152);

  prep_k<<<3836, 256, 0, stream>>>(x, atom_emb, A, W1, W2, Wt1, Wt2, cnt);

  // ---- CSR build (edge structure shared by all layers) ----
  hist_k<<<(NE + 255) / 256, 256, 0, stream>>>(ei, cnt);
  scan1_k<<<98, 256, 0, stream>>>(cnt, rowstart, bsum);
  scan3_k<<<(NN + 255) / 256, 256, 0, stream>>>(rowstart, bsum, cursor);
  scatter_k<<<8 * ((NE + 255) / 256), 256, 0, stream>>>(ei, eattr, cursor, epack);

  hipMemsetAsync(sbuf, 0, 61440, stream);
  for (int l = 0; l < NL; ++l) {
    float* stat1 = sbuf + (size_t)l * 3072;
    float* stat2 = sbuf + (size_t)l * 3072 + 2048;
    float* stat2p = sbuf + (size_t)(l - 1) * 3072 + 2048;
    if (l == 0)
      csr_aggr_k<0><<<NN / 32, 256, 0, stream>>>(rowstart, epack, bond_emb, A,
                                                 sbuf, gbn, bbn, B);
    else
      csr_aggr_k<1><<<NN / 32, 256, 0, stream>>>(rowstart, epack, bond_emb, A,
                                                 stat2p, gbn + (size_t)(l - 1) * 64,
                                                 bbn + (size_t)(l - 1) * 64, B);
    stat1_k<<<256, 256, 0, stream>>>(B, Wt1 + (size_t)l * 128 * 64, stat1);
    gemm12_k<<<NP / 64, 256, 0, stream>>>(B, Wt1 + (size_t)l * 128 * 64,
                                          Wt2 + (size_t)l * 64 * 128,
                                          stat1, g1 + (size_t)l * 128, be1 + (size_t)l * 128,
                                          b2 + (size_t)l * 64, A, stat2);
  }

  hipMemsetAsync(xpool, 0, (size_t)NG * 64 * 4, stream);
  final_k<<<NN / 16, 256, 0, stream>>>(A, sbuf + (size_t)(NL - 1) * 3072 + 2048,
                                       gbn + (size_t)(NL - 1) * 64,
                                       bbn + (size_t)(NL - 1) * 64, batch, hf, xpool);
}